// Round 6
// baseline (217.372 us; speedup 1.0000x reference)
//
#include <hip/hip_runtime.h>
#include <math.h>

#define HWSZ 4096   // 64*64
#define DIM  64
#define KCW  512
#define NROW 131072 // 32*4096
#define CMAX 16

typedef short bf16x8 __attribute__((ext_vector_type(8)));
typedef float f32x4  __attribute__((ext_vector_type(4)));

// ws float layout: [0] loss acc; [64..576) csq; [1024..17408) bf16 codebook blob
#define WS_CSQ  64
#define WS_BLOB 1024

static __device__ __forceinline__ unsigned short f2bf(float f) {
    union { float f; unsigned u; } v; v.f = f;
    unsigned u = v.u;
    return (unsigned short)((u + 0x7fffu + ((u >> 16) & 1u)) >> 16);  // RNE
}
static __device__ __forceinline__ float bf2f(unsigned short h) {
    union { unsigned u; float f; } v; v.u = ((unsigned)h) << 16;
    return v.f;
}

// prep: zero loss, exact fp32 csq, and codebook -> bf16 "fragment blob":
// blob[((kt*2+f)*64 + l)*8 + j] = bf16(cw[kt*16 + (l&15)][f*32 + (l>>4)*8 + j])
// (mirrors exactly how pass-1 lane l builds its A fragment slots, so any true
// HW slot->k permutation cancels between A and B.)
__global__ void vq_prep_kernel(const float* __restrict__ cw, float* __restrict__ ws) {
    int tg = blockIdx.x * 256 + threadIdx.x;
    if (tg == 0) ws[0] = 0.f;
    if (tg < KCW) {
        const float4* c4 = (const float4*)(cw + (size_t)tg * DIM);
        float s0 = 0.f, s1 = 0.f, s2 = 0.f, s3 = 0.f;
        #pragma unroll
        for (int i = 0; i < 16; ++i) {
            float4 c = c4[i];
            s0 = fmaf(c.x, c.x, s0); s1 = fmaf(c.y, c.y, s1);
            s2 = fmaf(c.z, c.z, s2); s3 = fmaf(c.w, c.w, s3);
        }
        ws[WS_CSQ + tg] = (s0 + s1) + (s2 + s3);
    }
    if (tg < 4096) {
        int l = tg & 63, f = (tg >> 6) & 1, kt = tg >> 7;
        int col = kt * 16 + (l & 15);
        unsigned short* blob = (unsigned short*)(ws + WS_BLOB);
        #pragma unroll
        for (int j = 0; j < 8; ++j) {
            int d = f * 32 + (l >> 4) * 8 + j;
            blob[((kt * 2 + f) * 64 + l) * 8 + j] = f2bf(cw[col * DIM + d]);
        }
    }
}

// One block = 64 rows x all 512 codewords. 4 waves, 16 rows/wave.
// Pass 1 (bf16 MFMA): score = csq/2 - dot, rolling fp32 row-min, bf16 scores in LDS.
// Pass 2: ballot-compact candidates within a rigorous error bound, exact fp32 refine.
__global__ __launch_bounds__(256, 4)
void vq_main_kernel(const float* __restrict__ in, const float* __restrict__ cw,
                    const float* __restrict__ ws_ro, float* __restrict__ loss_acc,
                    float* __restrict__ out) {
    __shared__ __align__(16) unsigned short sc[4][16][524];  // 67 KB scores; later aliased by xl
    __shared__ unsigned short cand[64][CMAX];
    __shared__ int   cnts[64];
    __shared__ float xsqa[64];
    __shared__ int   sidxl[64];
    __shared__ float redf[4];
    __shared__ int   redk[4];

    float* xl = (float*)&sc[0][0][0];          // [64][68] f32 x-tile, reuses sc space

    const float*  __restrict__ csqg = ws_ro + WS_CSQ;
    const bf16x8* __restrict__ bp   = (const bf16x8*)(ws_ro + WS_BLOB);

    const int t  = threadIdx.x;
    const int wv = t >> 6;
    const int l  = t & 63;
    const int g  = l >> 4;
    const int cl = l & 15;
    const int b    = blockIdx.x >> 6;          // 64 blocks per batch image
    const int hw0  = (blockIdx.x & 63) * 64;
    const int row0 = blockIdx.x * 64;

    // ---- Phase A: build A-fragments bf16(-x) for this lane's row (= wv*16+cl); approx xsq
    const float* __restrict__ xb = in + (size_t)b * (DIM * HWSZ) + hw0 + wv * 16 + cl;
    bf16x8 a0, a1;
    float xs_p = 0.f;
    #pragma unroll
    for (int j = 0; j < 8; ++j) {
        float xv = xb[(size_t)(g * 8 + j) * HWSZ];
        xs_p = fmaf(xv, xv, xs_p);
        a0[j] = (short)f2bf(-xv);
    }
    #pragma unroll
    for (int j = 0; j < 8; ++j) {
        float xv = xb[(size_t)(32 + g * 8 + j) * HWSZ];
        xs_p = fmaf(xv, xv, xs_p);
        a1[j] = (short)f2bf(-xv);
    }
    xs_p += __shfl_xor(xs_p, 16, 64);          // combine the 4 d-groups of this row
    xs_p += __shfl_xor(xs_p, 32, 64);
    if (g == 0) xsqa[wv * 16 + cl] = xs_p;

    // ---- Phase B: MFMA sweep (32 tiles of 16 codewords). acc = csq/2 - dot.
    float mn[4] = {INFINITY, INFINITY, INFINITY, INFINITY};
    #pragma unroll 2
    for (int kt = 0; kt < 32; ++kt) {
        float ci = 0.5f * csqg[kt * 16 + cl];
        f32x4 acc = {ci, ci, ci, ci};
        bf16x8 b0 = bp[(kt * 2 + 0) * 64 + l];
        bf16x8 b1 = bp[(kt * 2 + 1) * 64 + l];
        acc = __builtin_amdgcn_mfma_f32_16x16x32_bf16(a0, b0, acc, 0, 0, 0);
        acc = __builtin_amdgcn_mfma_f32_16x16x32_bf16(a1, b1, acc, 0, 0, 0);
        // D layout (HW-verified): col = lane&15, row = 4*(lane>>4)+reg
        #pragma unroll
        for (int rg = 0; rg < 4; ++rg) {
            float v = acc[rg];
            mn[rg] = fminf(mn[rg], v);
            sc[wv][4 * g + rg][kt * 16 + cl] = f2bf(v);
        }
    }
    #pragma unroll
    for (int off = 1; off < 16; off <<= 1) {   // row-min across the 16 col-lanes
        #pragma unroll
        for (int rg = 0; rg < 4; ++rg)
            mn[rg] = fminf(mn[rg], __shfl_xor(mn[rg], off, 64));
    }
    __syncthreads();

    // ---- Phase C: candidate compaction. Bound: |s~ - s| <= ||x||/16 (bf16 inputs,
    // products exact in fp32) + 0.15 (bf16 score storage). thr = mn + 2*beta + margin.
    int cnt[4] = {0, 0, 0, 0};
    float thr[4];
    #pragma unroll
    for (int rg = 0; rg < 4; ++rg)
        thr[rg] = mn[rg] + 0.125f * sqrtf(xsqa[wv * 16 + 4 * g + rg]) + 0.5f;
    for (int kt = 0; kt < 32; ++kt) {
        #pragma unroll
        for (int rg = 0; rg < 4; ++rg) {
            float s = bf2f(sc[wv][4 * g + rg][kt * 16 + cl]);
            bool flag = (s <= thr[rg]);
            unsigned long long bal = __ballot(flag);
            unsigned m16 = (unsigned)(bal >> (g * 16)) & 0xffffu;
            int pos = cnt[rg] + __popc(m16 & ((1u << cl) - 1u));
            if (flag && pos < CMAX)
                cand[wv * 16 + 4 * g + rg][pos] = (unsigned short)(kt * 16 + cl);
            cnt[rg] += __popc(m16);            // ascending k order preserved
        }
    }
    if (cl == 0) {
        #pragma unroll
        for (int rg = 0; rg < 4; ++rg) cnts[wv * 16 + 4 * g + rg] = cnt[rg];
    }
    __syncthreads();                            // all waves done with sc before xl overwrite

    // ---- Phase D: stage exact fp32 x-tile (aliases sc), refine candidates exactly
    {
        const int tx = t & 15, ty = t >> 4;
        const float* __restrict__ xb2 = in + (size_t)b * (DIM * HWSZ) + hw0;
        #pragma unroll
        for (int p = 0; p < 4; ++p) {
            int d = p * 16 + ty;
            *(float4*)(xl + d * 68 + tx * 4) = *(const float4*)(xb2 + (size_t)d * HWSZ + tx * 4);
        }
    }
    __syncthreads();

    if (t < 64) {
        const int r = t;
        float xsqe = 0.f;
        for (int d = 0; d < DIM; ++d) { float xv = xl[d * 68 + r]; xsqe = fmaf(xv, xv, xsqe); }
        int n = cnts[r];
        if (n <= CMAX) {
            float best = INFINITY; int bk = 0;
            for (int s = 0; s < n; ++s) {
                int k = cand[r][s];
                const float* __restrict__ c = cw + (size_t)k * DIM;
                float d0 = 0.f, d1 = 0.f, d2 = 0.f, d3 = 0.f;
                #pragma unroll
                for (int i = 0; i < 16; ++i) {
                    d0 = fmaf(xl[(4 * i + 0) * 68 + r], c[4 * i + 0], d0);
                    d1 = fmaf(xl[(4 * i + 1) * 68 + r], c[4 * i + 1], d1);
                    d2 = fmaf(xl[(4 * i + 2) * 68 + r], c[4 * i + 2], d2);
                    d3 = fmaf(xl[(4 * i + 3) * 68 + r], c[4 * i + 3], d3);
                }
                float dot  = (d0 + d1) + (d2 + d3);
                float dist = (xsqe + csqg[k]) - 2.f * dot;       // reference rounding order
                if (dist < best) { best = dist; bk = k; }        // ascending k: ties -> lowest
            }
            sidxl[r] = bk;
            out[(size_t)NROW * DIM + row0 + r] = (float)bk;
        }
    }
    __syncthreads();

    // ---- rare overflow rows (cnt > CMAX): cooperative exact full scan (deterministic)
    for (int r = 0; r < 64; ++r) {
        if (cnts[r] <= CMAX) continue;                            // uniform (LDS)
        float xsqe = 0.f;
        for (int d = 0; d < DIM; ++d) { float xv = xl[d * 68 + r]; xsqe = fmaf(xv, xv, xsqe); }
        float bb = INFINITY; int bkk = 0x7fffffff;
        for (int k = t; k < KCW; k += 256) {
            const float* __restrict__ c = cw + (size_t)k * DIM;
            float d0 = 0.f, d1 = 0.f, d2 = 0.f, d3 = 0.f;
            #pragma unroll
            for (int i = 0; i < 16; ++i) {
                d0 = fmaf(xl[(4 * i + 0) * 68 + r], c[4 * i + 0], d0);
                d1 = fmaf(xl[(4 * i + 1) * 68 + r], c[4 * i + 1], d1);
                d2 = fmaf(xl[(4 * i + 2) * 68 + r], c[4 * i + 2], d2);
                d3 = fmaf(xl[(4 * i + 3) * 68 + r], c[4 * i + 3], d3);
            }
            float dot  = (d0 + d1) + (d2 + d3);
            float dist = (xsqe + csqg[k]) - 2.f * dot;
            if (dist < bb || (dist == bb && k < bkk)) { bb = dist; bkk = k; }
        }
        #pragma unroll
        for (int off = 32; off; off >>= 1) {
            float ob = __shfl_down(bb, off, 64);
            int   ok = __shfl_down(bkk, off, 64);
            if (ob < bb || (ob == bb && ok < bkk)) { bb = ob; bkk = ok; }
        }
        if (l == 0) { redf[wv] = bb; redk[wv] = bkk; }
        __syncthreads();
        if (t == 0) {
            float fb = redf[0]; int fk = redk[0];
            for (int w2 = 1; w2 < 4; ++w2)
                if (redf[w2] < fb || (redf[w2] == fb && redk[w2] < fk)) { fb = redf[w2]; fk = redk[w2]; }
            sidxl[r] = fk;
            out[(size_t)NROW * DIM + row0 + r] = (float)fk;
        }
        __syncthreads();
    }

    // ---- Phase E: epilogue — gather codeword, write quantized NCHW, loss partial
    {
        const int gr = t & 63, seg = t >> 6;                      // seg wave-uniform
        const int kwin = sidxl[gr];
        const float* __restrict__ qp = cw + (size_t)kwin * DIM + seg * 16;
        float* __restrict__ obase = out + (size_t)b * (DIM * HWSZ) + hw0 + gr;
        float lsum = 0.f;
        #pragma unroll
        for (int dd = 0; dd < 4; ++dd) {
            float4 q4 = *(const float4*)(qp + dd * 4);
            float qv[4] = {q4.x, q4.y, q4.z, q4.w};
            #pragma unroll
            for (int c = 0; c < 4; ++c) {
                int d = seg * 16 + dd * 4 + c;
                float xv = xl[d * 68 + gr];
                obase[(size_t)d * HWSZ] = qv[c];
                float diff = qv[c] - xv;
                lsum = fmaf(diff, diff, lsum);
            }
        }
        #pragma unroll
        for (int off = 32; off; off >>= 1) lsum += __shfl_down(lsum, off, 64);
        if (l == 0) atomicAdd(loss_acc, lsum);
    }
}

__global__ void vq_finalize_kernel(const float* __restrict__ ws, float* __restrict__ out) {
    out[(size_t)NROW * DIM + NROW] = 1.25f * ws[0] / (float)((size_t)NROW * DIM);
}

extern "C" void kernel_launch(void* const* d_in, const int* in_sizes, int n_in,
                              void* d_out, int out_size, void* d_ws, size_t ws_size,
                              hipStream_t stream) {
    const float* in = (const float*)d_in[0];
    const float* cw = (const float*)d_in[1];
    float* out = (float*)d_out;
    float* ws  = (float*)d_ws;

    hipLaunchKernelGGL(vq_prep_kernel, dim3(16), dim3(256), 0, stream, cw, ws);
    hipLaunchKernelGGL(vq_main_kernel, dim3(NROW / 64), dim3(256), 0, stream,
                       in, cw, ws, ws, out);
    hipLaunchKernelGGL(vq_finalize_kernel, dim3(1), dim3(1), 0, stream, ws, out);
}

// Round 7
// 167.157 us; speedup vs baseline: 1.3004x; 1.3004x over previous
//
#include <hip/hip_runtime.h>
#include <math.h>

#define HWSZ 4096   // 64*64
#define DIM  64
#define KCW  512
#define NROW 131072 // 32*4096
#define CMAX 16
#define XP   68     // x-tile pitch (floats)

typedef short bf16x8 __attribute__((ext_vector_type(8)));
typedef float f32x4  __attribute__((ext_vector_type(4)));

// ws float layout: [0] loss acc; [64..576) csq; [1024..17408) bf16 codebook blob
#define WS_CSQ  64
#define WS_BLOB 1024

static __device__ __forceinline__ unsigned short f2bf(float f) {
    union { float f; unsigned u; } v; v.f = f;
    unsigned u = v.u;
    return (unsigned short)((u + 0x7fffu + ((u >> 16) & 1u)) >> 16);  // RNE
}

// prep: zero loss, exact fp32 csq, codebook -> bf16 fragment blob:
// blob[((kt*2+f)*64 + l)*8 + j] = bf16(cw[kt*16 + (l&15)][f*32 + (l>>4)*8 + j])
// (mirrors pass-1 lane fragment construction; verified by R6 passing at 2^-10.)
__global__ void vq_prep_kernel(const float* __restrict__ cw, float* __restrict__ ws) {
    int tg = blockIdx.x * 256 + threadIdx.x;
    if (tg == 0) ws[0] = 0.f;
    if (tg < KCW) {
        const float4* c4 = (const float4*)(cw + (size_t)tg * DIM);
        float s0 = 0.f, s1 = 0.f, s2 = 0.f, s3 = 0.f;
        #pragma unroll
        for (int i = 0; i < 16; ++i) {
            float4 c = c4[i];
            s0 = fmaf(c.x, c.x, s0); s1 = fmaf(c.y, c.y, s1);
            s2 = fmaf(c.z, c.z, s2); s3 = fmaf(c.w, c.w, s3);
        }
        ws[WS_CSQ + tg] = (s0 + s1) + (s2 + s3);
    }
    if (tg < 4096) {
        int l = tg & 63, f = (tg >> 6) & 1, kt = tg >> 7;
        int col = kt * 16 + (l & 15);
        unsigned short* blob = (unsigned short*)(ws + WS_BLOB);
        #pragma unroll
        for (int j = 0; j < 8; ++j) {
            int d = f * 32 + (l >> 4) * 8 + j;
            blob[((kt * 2 + f) * 64 + l) * 8 + j] = f2bf(cw[col * DIM + d]);
        }
    }
}

// One block = 64 rows x 512 codewords. Two register-only MFMA sweeps (min, then
// candidates via LDS-atomic insert), exact fp32 refine by 4 threads/row.
__global__ __launch_bounds__(256, 4)
void vq_main_kernel(const float* __restrict__ in, const float* __restrict__ cw,
                    const float* __restrict__ ws_ro, float* __restrict__ loss_acc,
                    float* __restrict__ out) {
    __shared__ __align__(16) float xl[DIM * XP];   // 17.4 KB fp32 x-tile [d][row]
    __shared__ unsigned short cand[64][CMAX];      // 2 KB
    __shared__ int   cnts[64];
    __shared__ float xsqa[64];
    __shared__ int   sidxl[64];
    __shared__ float redf[4];
    __shared__ int   redk[4];

    const float*  __restrict__ csqg = ws_ro + WS_CSQ;
    const bf16x8* __restrict__ bp   = (const bf16x8*)(ws_ro + WS_BLOB);

    const int t  = threadIdx.x;
    const int wv = t >> 6, l = t & 63, g = l >> 4, cl = l & 15;
    const int b    = blockIdx.x >> 6;
    const int hw0  = (blockIdx.x & 63) * 64;
    const int row0 = blockIdx.x * 64;

    if (t < 64) cnts[t] = 0;

    // ---- stage x tile (global read happens exactly once per block)
    {
        const int tx = t & 15, ty = t >> 4;
        const float* __restrict__ xb = in + (size_t)b * (DIM * HWSZ) + hw0;
        #pragma unroll
        for (int p = 0; p < 4; ++p) {
            int d = p * 16 + ty;
            *(float4*)(xl + d * XP + tx * 4) = *(const float4*)(xb + (size_t)d * HWSZ + tx * 4);
        }
    }
    __syncthreads();

    // ---- exact ||x||^2: thread t -> row t>>2, dim-quarter t&3; 4-lane reduce
    {
        int r = t >> 2, q = t & 3;
        float s = 0.f;
        #pragma unroll
        for (int i = 0; i < 16; ++i) {
            float xv = xl[(q * 16 + i) * XP + r];
            s = fmaf(xv, xv, s);
        }
        s += __shfl_xor(s, 1, 64);
        s += __shfl_xor(s, 2, 64);
        if (q == 0) xsqa[r] = s;     // writer and readers are the same wave
    }

    // ---- A fragments bf16(-x) straight from LDS (row = wv*16+cl, d-slots by g)
    const int myrow = wv * 16 + cl;
    bf16x8 a0, a1;
    #pragma unroll
    for (int j = 0; j < 8; ++j) a0[j] = (short)f2bf(-xl[(g * 8 + j) * XP + myrow]);
    #pragma unroll
    for (int j = 0; j < 8; ++j) a1[j] = (short)f2bf(-xl[(32 + g * 8 + j) * XP + myrow]);

    // ---- sweep 1: per-row min of score s = csq/2 - dot (fp32, in-register)
    float mn[4] = {INFINITY, INFINITY, INFINITY, INFINITY};
    #pragma unroll 2
    for (int kt = 0; kt < 32; ++kt) {
        float ci = 0.5f * csqg[kt * 16 + cl];
        f32x4 acc = {ci, ci, ci, ci};
        bf16x8 b0 = bp[(kt * 2 + 0) * 64 + l];
        bf16x8 b1 = bp[(kt * 2 + 1) * 64 + l];
        acc = __builtin_amdgcn_mfma_f32_16x16x32_bf16(a0, b0, acc, 0, 0, 0);
        acc = __builtin_amdgcn_mfma_f32_16x16x32_bf16(a1, b1, acc, 0, 0, 0);
        #pragma unroll
        for (int rg = 0; rg < 4; ++rg) mn[rg] = fminf(mn[rg], acc[rg]);
    }
    #pragma unroll
    for (int off = 1; off < 16; off <<= 1)
        #pragma unroll
        for (int rg = 0; rg < 4; ++rg)
            mn[rg] = fminf(mn[rg], __shfl_xor(mn[rg], off, 64));

    // bound: 2*beta = ||x||/16 (bf16 u=2^-9, ||c||<=8) + 0.25 margin
    float thr[4];
    #pragma unroll
    for (int rg = 0; rg < 4; ++rg)
        thr[rg] = mn[rg] + 0.0625f * sqrtf(xsqa[wv * 16 + 4 * g + rg]) + 0.25f;

    // ---- sweep 2: recompute scores, insert candidates via LDS-atomic counters
    #pragma unroll 2
    for (int kt = 0; kt < 32; ++kt) {
        float ci = 0.5f * csqg[kt * 16 + cl];
        f32x4 acc = {ci, ci, ci, ci};
        bf16x8 b0 = bp[(kt * 2 + 0) * 64 + l];
        bf16x8 b1 = bp[(kt * 2 + 1) * 64 + l];
        acc = __builtin_amdgcn_mfma_f32_16x16x32_bf16(a0, b0, acc, 0, 0, 0);
        acc = __builtin_amdgcn_mfma_f32_16x16x32_bf16(a1, b1, acc, 0, 0, 0);
        #pragma unroll
        for (int rg = 0; rg < 4; ++rg) {
            if (acc[rg] <= thr[rg]) {
                int r = wv * 16 + 4 * g + rg;          // rows are wave-private
                int pos = atomicAdd(&cnts[r], 1);
                if (pos < CMAX) cand[r][pos] = (unsigned short)(kt * 16 + cl);
            }
        }
    }
    __syncthreads();

    // ---- exact fp32 refine: 4 slot-threads per row, lex (dist,k) tie-break
    {
        const int rr = t >> 2, slot = t & 3;
        const int n = cnts[rr];
        if (n <= CMAX) {
            float bb = INFINITY; int bkk = 0x7fffffff;
            const float xsqe = xsqa[rr];
            for (int s = slot; s < n; s += 4) {
                int k = cand[rr][s];
                const float4* __restrict__ c4 = (const float4*)(cw + (size_t)k * DIM);
                float d0 = 0.f, d1 = 0.f, d2 = 0.f, d3 = 0.f;
                #pragma unroll
                for (int i = 0; i < 16; ++i) {
                    float4 c = c4[i];
                    d0 = fmaf(xl[(4 * i + 0) * XP + rr], c.x, d0);
                    d1 = fmaf(xl[(4 * i + 1) * XP + rr], c.y, d1);
                    d2 = fmaf(xl[(4 * i + 2) * XP + rr], c.z, d2);
                    d3 = fmaf(xl[(4 * i + 3) * XP + rr], c.w, d3);
                }
                float dot  = (d0 + d1) + (d2 + d3);
                float dist = (xsqe + csqg[k]) - 2.f * dot;
                if (dist < bb || (dist == bb && k < bkk)) { bb = dist; bkk = k; }
            }
            #pragma unroll
            for (int off = 1; off < 4; off <<= 1) {
                float ob = __shfl_xor(bb, off, 64);
                int   ok = __shfl_xor(bkk, off, 64);
                if (ob < bb || (ob == bb && ok < bkk)) { bb = ob; bkk = ok; }
            }
            if (slot == 0) {
                sidxl[rr] = bkk;
                out[(size_t)NROW * DIM + row0 + rr] = (float)bkk;
            }
        }
    }
    __syncthreads();

    // ---- rare overflow rows (cnt > CMAX): cooperative exact full scan
    for (int r = 0; r < 64; ++r) {
        if (cnts[r] <= CMAX) continue;                 // block-uniform
        const float xsqe = xsqa[r];
        float bb = INFINITY; int bkk = 0x7fffffff;
        for (int k = t; k < KCW; k += 256) {
            const float4* __restrict__ c4 = (const float4*)(cw + (size_t)k * DIM);
            float d0 = 0.f, d1 = 0.f, d2 = 0.f, d3 = 0.f;
            #pragma unroll
            for (int i = 0; i < 16; ++i) {
                float4 c = c4[i];
                d0 = fmaf(xl[(4 * i + 0) * XP + r], c.x, d0);
                d1 = fmaf(xl[(4 * i + 1) * XP + r], c.y, d1);
                d2 = fmaf(xl[(4 * i + 2) * XP + r], c.z, d2);
                d3 = fmaf(xl[(4 * i + 3) * XP + r], c.w, d3);
            }
            float dot  = (d0 + d1) + (d2 + d3);
            float dist = (xsqe + csqg[k]) - 2.f * dot;
            if (dist < bb || (dist == bb && k < bkk)) { bb = dist; bkk = k; }
        }
        #pragma unroll
        for (int off = 32; off; off >>= 1) {
            float ob = __shfl_down(bb, off, 64);
            int   ok = __shfl_down(bkk, off, 64);
            if (ob < bb || (ob == bb && ok < bkk)) { bb = ob; bkk = ok; }
        }
        if (l == 0) { redf[wv] = bb; redk[wv] = bkk; }
        __syncthreads();
        if (t == 0) {
            float fb = redf[0]; int fk = redk[0];
            for (int w2 = 1; w2 < 4; ++w2)
                if (redf[w2] < fb || (redf[w2] == fb && redk[w2] < fk)) { fb = redf[w2]; fk = redk[w2]; }
            sidxl[r] = fk;
            out[(size_t)NROW * DIM + row0 + r] = (float)fk;
        }
        __syncthreads();
    }

    // ---- epilogue: gather codeword, write quantized NCHW, loss partial
    {
        const int gr = t & 63, seg = t >> 6;           // seg wave-uniform
        const int kwin = sidxl[gr];
        const float* __restrict__ qp = cw + (size_t)kwin * DIM + seg * 16;
        float* __restrict__ obase = out + (size_t)b * (DIM * HWSZ) + hw0 + gr;
        float lsum = 0.f;
        #pragma unroll
        for (int dd = 0; dd < 4; ++dd) {
            float4 q4 = *(const float4*)(qp + dd * 4);
            float qv[4] = {q4.x, q4.y, q4.z, q4.w};
            #pragma unroll
            for (int c = 0; c < 4; ++c) {
                int d = seg * 16 + dd * 4 + c;
                float xv = xl[d * XP + gr];
                obase[(size_t)d * HWSZ] = qv[c];
                float diff = qv[c] - xv;
                lsum = fmaf(diff, diff, lsum);
            }
        }
        #pragma unroll
        for (int off = 32; off; off >>= 1) lsum += __shfl_down(lsum, off, 64);
        if (l == 0) atomicAdd(loss_acc, lsum);
    }
}

__global__ void vq_finalize_kernel(const float* __restrict__ ws, float* __restrict__ out) {
    out[(size_t)NROW * DIM + NROW] = 1.25f * ws[0] / (float)((size_t)NROW * DIM);
}

extern "C" void kernel_launch(void* const* d_in, const int* in_sizes, int n_in,
                              void* d_out, int out_size, void* d_ws, size_t ws_size,
                              hipStream_t stream) {
    const float* in = (const float*)d_in[0];
    const float* cw = (const float*)d_in[1];
    float* out = (float*)d_out;
    float* ws  = (float*)d_ws;

    hipLaunchKernelGGL(vq_prep_kernel, dim3(16), dim3(256), 0, stream, cw, ws);
    hipLaunchKernelGGL(vq_main_kernel, dim3(NROW / 64), dim3(256), 0, stream,
                       in, cw, ws, ws, out);
    hipLaunchKernelGGL(vq_finalize_kernel, dim3(1), dim3(1), 0, stream, ws, out);
}

// Round 8
// 133.754 us; speedup vs baseline: 1.6252x; 1.2497x over previous
//
#include <hip/hip_runtime.h>
#include <math.h>

#define HWSZ 4096   // 64*64
#define DIM  64
#define KCW  512
#define NROW 131072 // 32*4096
#define CMAX 16
#define XP   68     // x-tile pitch (floats)

typedef short bf16x8 __attribute__((ext_vector_type(8)));
typedef float f32x4  __attribute__((ext_vector_type(4)));

// ws float layout: [64..576) csq; [1024..17408) bf16 blob; [17408..19456) loss partials
#define WS_CSQ  64
#define WS_BLOB 1024
#define WS_PART 17408

static __device__ __forceinline__ unsigned short f2bf(float f) {
    union { float f; unsigned u; } v; v.f = f;
    unsigned u = v.u;
    return (unsigned short)((u + 0x7fffu + ((u >> 16) & 1u)) >> 16);  // RNE
}

// prep: exact fp32 csq, codebook -> bf16 fragment blob
// blob[((kt*2+f)*64 + l)*8 + j] = bf16(cw[kt*16 + (l&15)][f*32 + (l>>4)*8 + j])
__global__ void vq_prep_kernel(const float* __restrict__ cw, float* __restrict__ ws) {
    int tg = blockIdx.x * 256 + threadIdx.x;
    if (tg < KCW) {
        const float4* c4 = (const float4*)(cw + (size_t)tg * DIM);
        float s0 = 0.f, s1 = 0.f, s2 = 0.f, s3 = 0.f;
        #pragma unroll
        for (int i = 0; i < 16; ++i) {
            float4 c = c4[i];
            s0 = fmaf(c.x, c.x, s0); s1 = fmaf(c.y, c.y, s1);
            s2 = fmaf(c.z, c.z, s2); s3 = fmaf(c.w, c.w, s3);
        }
        ws[WS_CSQ + tg] = (s0 + s1) + (s2 + s3);
    }
    if (tg < 4096) {
        int l = tg & 63, f = (tg >> 6) & 1, kt = tg >> 7;
        int col = kt * 16 + (l & 15);
        unsigned short* blob = (unsigned short*)(ws + WS_BLOB);
        #pragma unroll
        for (int j = 0; j < 8; ++j) {
            int d = f * 32 + (l >> 4) * 8 + j;
            blob[((kt * 2 + f) * 64 + l) * 8 + j] = f2bf(cw[col * DIM + d]);
        }
    }
}

// One block = 64 rows x 512 codewords. 8 waves: wave w -> row-group (w&3),
// codebook half (w>>2). Two MFMA sweeps (min, then LDS-atomic candidate insert),
// exact fp32 refine (8 threads/row), per-block loss partial (no global atomic).
__global__ __launch_bounds__(512, 8)
void vq_main_kernel(const float* __restrict__ in, const float* __restrict__ cw,
                    const float* __restrict__ ws_ro, float* __restrict__ part,
                    float* __restrict__ out) {
    __shared__ __align__(16) float xl[DIM * XP];   // 17.4 KB fp32 x-tile [d][row]
    __shared__ unsigned short cand[64][CMAX];      // 2 KB
    __shared__ int   cnts[64];
    __shared__ float xsqa[64];
    __shared__ int   sidxl[64];
    __shared__ float mnh[64][2];                   // per-row min, per kt-half
    __shared__ float redf[8];
    __shared__ int   redk[8];
    __shared__ float lossb;

    const float*  __restrict__ csqg = ws_ro + WS_CSQ;
    const bf16x8* __restrict__ bp   = (const bf16x8*)(ws_ro + WS_BLOB);

    const int t  = threadIdx.x;
    const int w  = t >> 6, l = t & 63, g = l >> 4, cl = l & 15;
    const int h  = w >> 2;            // codebook half (kt 16h .. 16h+15)
    const int wr = w & 3;             // row-group (rows 16wr .. 16wr+15)
    const int b    = blockIdx.x >> 6;
    const int hw0  = (blockIdx.x & 63) * 64;
    const int row0 = blockIdx.x * 64;

    if (t < 64) cnts[t] = 0;
    if (t == 0) lossb = 0.f;

    // ---- stage x tile (single global read of this block's input)
    {
        const int tx = t & 15, ty = t >> 4;       // ty 0..31
        const float* __restrict__ xb = in + (size_t)b * (DIM * HWSZ) + hw0;
        #pragma unroll
        for (int p = 0; p < 2; ++p) {
            int d = p * 32 + ty;
            *(float4*)(xl + d * XP + tx * 4) = *(const float4*)(xb + (size_t)d * HWSZ + tx * 4);
        }
    }
    __syncthreads();

    // ---- exact ||x||^2: row t>>3, dim-eighth t&7, 8-lane shuffle reduce
    {
        int r = t >> 3, q = t & 7;
        float s = 0.f;
        #pragma unroll
        for (int i = 0; i < 8; ++i) {
            float xv = xl[(q * 8 + i) * XP + r];
            s = fmaf(xv, xv, s);
        }
        s += __shfl_xor(s, 1, 64);
        s += __shfl_xor(s, 2, 64);
        s += __shfl_xor(s, 4, 64);
        if (q == 0) xsqa[r] = s;                  // consumed after the mnh barrier
    }

    // ---- A fragments bf16(-x): row = wr*16+cl, d-slots by g
    const int myrow = wr * 16 + cl;
    bf16x8 a0, a1;
    #pragma unroll
    for (int j = 0; j < 8; ++j) a0[j] = (short)f2bf(-xl[(g * 8 + j) * XP + myrow]);
    #pragma unroll
    for (int j = 0; j < 8; ++j) a1[j] = (short)f2bf(-xl[(32 + g * 8 + j) * XP + myrow]);

    // ---- sweep 1: per-row min of score s = csq/2 - dot over this wave's 16 kt
    float mn[4] = {INFINITY, INFINITY, INFINITY, INFINITY};
    #pragma unroll 4
    for (int k2 = 0; k2 < 16; ++k2) {
        const int kt = h * 16 + k2;
        float ci = 0.5f * csqg[kt * 16 + cl];
        f32x4 acc = {ci, ci, ci, ci};
        bf16x8 b0 = bp[(kt * 2 + 0) * 64 + l];
        bf16x8 b1 = bp[(kt * 2 + 1) * 64 + l];
        acc = __builtin_amdgcn_mfma_f32_16x16x32_bf16(a0, b0, acc, 0, 0, 0);
        acc = __builtin_amdgcn_mfma_f32_16x16x32_bf16(a1, b1, acc, 0, 0, 0);
        #pragma unroll
        for (int rg = 0; rg < 4; ++rg) mn[rg] = fminf(mn[rg], acc[rg]);
    }
    #pragma unroll
    for (int off = 1; off < 16; off <<= 1)        // min over the 16 col-lanes
        #pragma unroll
        for (int rg = 0; rg < 4; ++rg)
            mn[rg] = fminf(mn[rg], __shfl_xor(mn[rg], off, 64));
    if (cl == 0) {
        #pragma unroll
        for (int rg = 0; rg < 4; ++rg) mnh[wr * 16 + 4 * g + rg][h] = mn[rg];
    }
    __syncthreads();

    // bound: 2*beta = ||x||/16 (bf16 u=2^-9, ||c||<=8) + 0.25 margin (R6/R7-proven)
    float thr[4];
    #pragma unroll
    for (int rg = 0; rg < 4; ++rg) {
        int r = wr * 16 + 4 * g + rg;
        float m = fminf(mnh[r][0], mnh[r][1]);
        thr[rg] = m + 0.0625f * sqrtf(xsqa[r]) + 0.25f;
    }

    // ---- sweep 2: recompute, insert candidates (order races; refine is lex-safe)
    #pragma unroll 4
    for (int k2 = 0; k2 < 16; ++k2) {
        const int kt = h * 16 + k2;
        float ci = 0.5f * csqg[kt * 16 + cl];
        f32x4 acc = {ci, ci, ci, ci};
        bf16x8 b0 = bp[(kt * 2 + 0) * 64 + l];
        bf16x8 b1 = bp[(kt * 2 + 1) * 64 + l];
        acc = __builtin_amdgcn_mfma_f32_16x16x32_bf16(a0, b0, acc, 0, 0, 0);
        acc = __builtin_amdgcn_mfma_f32_16x16x32_bf16(a1, b1, acc, 0, 0, 0);
        #pragma unroll
        for (int rg = 0; rg < 4; ++rg) {
            if (acc[rg] <= thr[rg]) {
                int r = wr * 16 + 4 * g + rg;
                int pos = atomicAdd(&cnts[r], 1);
                if (pos < CMAX) cand[r][pos] = (unsigned short)(kt * 16 + cl);
            }
        }
    }
    __syncthreads();

    // ---- exact fp32 refine: 8 slot-threads per row, lex (dist,k) tie-break
    {
        const int rr = t >> 3, slot = t & 7;
        const int n = cnts[rr];
        if (n <= CMAX) {                          // n >= 1 always (min qualifies)
            float bb = INFINITY; int bkk = 0x7fffffff;
            const float xsqe = xsqa[rr];
            for (int s = slot; s < n; s += 8) {
                int k = cand[rr][s];
                const float4* __restrict__ c4 = (const float4*)(cw + (size_t)k * DIM);
                float d0 = 0.f, d1 = 0.f, d2 = 0.f, d3 = 0.f;
                #pragma unroll
                for (int i = 0; i < 16; ++i) {
                    float4 c = c4[i];
                    d0 = fmaf(xl[(4 * i + 0) * XP + rr], c.x, d0);
                    d1 = fmaf(xl[(4 * i + 1) * XP + rr], c.y, d1);
                    d2 = fmaf(xl[(4 * i + 2) * XP + rr], c.z, d2);
                    d3 = fmaf(xl[(4 * i + 3) * XP + rr], c.w, d3);
                }
                float dot  = (d0 + d1) + (d2 + d3);
                float dist = (xsqe + csqg[k]) - 2.f * dot;   // reference rounding order
                if (dist < bb || (dist == bb && k < bkk)) { bb = dist; bkk = k; }
            }
            #pragma unroll
            for (int off = 1; off < 8; off <<= 1) {
                float ob = __shfl_xor(bb, off, 64);
                int   ok = __shfl_xor(bkk, off, 64);
                if (ob < bb || (ob == bb && ok < bkk)) { bb = ob; bkk = ok; }
            }
            if (slot == 0) {
                sidxl[rr] = bkk;
                out[(size_t)NROW * DIM + row0 + rr] = (float)bkk;
            }
        }
    }
    __syncthreads();

    // ---- rare overflow rows: one codeword per thread, block lex-argmin
    for (int r = 0; r < 64; ++r) {
        if (cnts[r] <= CMAX) continue;            // block-uniform
        const float xsqe = xsqa[r];
        const int k = t;                          // 512 threads = 512 codewords
        const float4* __restrict__ c4 = (const float4*)(cw + (size_t)k * DIM);
        float d0 = 0.f, d1 = 0.f, d2 = 0.f, d3 = 0.f;
        #pragma unroll
        for (int i = 0; i < 16; ++i) {
            float4 c = c4[i];
            d0 = fmaf(xl[(4 * i + 0) * XP + r], c.x, d0);
            d1 = fmaf(xl[(4 * i + 1) * XP + r], c.y, d1);
            d2 = fmaf(xl[(4 * i + 2) * XP + r], c.z, d2);
            d3 = fmaf(xl[(4 * i + 3) * XP + r], c.w, d3);
        }
        float dot = (d0 + d1) + (d2 + d3);
        float bb  = (xsqe + csqg[k]) - 2.f * dot;
        int  bkk  = k;
        #pragma unroll
        for (int off = 32; off; off >>= 1) {
            float ob = __shfl_down(bb, off, 64);
            int   ok = __shfl_down(bkk, off, 64);
            if (ob < bb || (ob == bb && ok < bkk)) { bb = ob; bkk = ok; }
        }
        if (l == 0) { redf[w] = bb; redk[w] = bkk; }
        __syncthreads();
        if (t == 0) {
            float fb = redf[0]; int fk = redk[0];
            for (int w2 = 1; w2 < 8; ++w2)
                if (redf[w2] < fb || (redf[w2] == fb && redk[w2] < fk)) { fb = redf[w2]; fk = redk[w2]; }
            sidxl[r] = fk;
            out[(size_t)NROW * DIM + row0 + r] = (float)fk;
        }
        __syncthreads();
    }

    // ---- epilogue: gather codeword, write quantized NCHW, loss partial
    {
        const int gr = t & 63, seg = t >> 6;      // seg wave-uniform (0..7), 8 dims each
        const int kwin = sidxl[gr];
        const float* __restrict__ qp = cw + (size_t)kwin * DIM + seg * 8;
        float* __restrict__ obase = out + (size_t)b * (DIM * HWSZ) + hw0 + gr;
        float lsum = 0.f;
        #pragma unroll
        for (int dd = 0; dd < 2; ++dd) {
            float4 q4 = *(const float4*)(qp + dd * 4);
            float qv[4] = {q4.x, q4.y, q4.z, q4.w};
            #pragma unroll
            for (int c = 0; c < 4; ++c) {
                int d = seg * 8 + dd * 4 + c;
                float xv = xl[d * XP + gr];
                obase[(size_t)d * HWSZ] = qv[c];
                float diff = qv[c] - xv;
                lsum = fmaf(diff, diff, lsum);
            }
        }
        #pragma unroll
        for (int off = 32; off; off >>= 1) lsum += __shfl_down(lsum, off, 64);
        if (l == 0) atomicAdd(&lossb, lsum);
    }
    __syncthreads();
    if (t == 0) part[blockIdx.x] = lossb;
}

__global__ void vq_finalize_kernel(const float* __restrict__ part, float* __restrict__ out) {
    __shared__ float wsum[4];
    const int t = threadIdx.x;
    float s = 0.f;
    #pragma unroll
    for (int i = 0; i < 8; ++i) s += part[t * 8 + i];   // fixed order: deterministic
    #pragma unroll
    for (int off = 32; off; off >>= 1) s += __shfl_down(s, off, 64);
    if ((t & 63) == 0) wsum[t >> 6] = s;
    __syncthreads();
    if (t == 0)
        out[(size_t)NROW * DIM + NROW] =
            1.25f * ((wsum[0] + wsum[1]) + (wsum[2] + wsum[3])) / (float)((size_t)NROW * DIM);
}

extern "C" void kernel_launch(void* const* d_in, const int* in_sizes, int n_in,
                              void* d_out, int out_size, void* d_ws, size_t ws_size,
                              hipStream_t stream) {
    const float* in = (const float*)d_in[0];
    const float* cw = (const float*)d_in[1];
    float* out = (float*)d_out;
    float* ws  = (float*)d_ws;

    hipLaunchKernelGGL(vq_prep_kernel, dim3(16), dim3(256), 0, stream, cw, ws);
    hipLaunchKernelGGL(vq_main_kernel, dim3(NROW / 64), dim3(512), 0, stream,
                       in, cw, ws, ws + WS_PART, out);
    hipLaunchKernelGGL(vq_finalize_kernel, dim3(1), dim3(256), 0, stream, ws + WS_PART, out);
}

// Round 9
// 119.905 us; speedup vs baseline: 1.8129x; 1.1155x over previous
//
#include <hip/hip_runtime.h>
#include <math.h>

#define HWSZ 4096   // 64*64
#define DIM  64
#define KCW  512
#define NROW 131072 // 32*4096
#define CMAX 16
#define XP   68     // x-tile pitch (floats)

typedef short bf16x8 __attribute__((ext_vector_type(8)));
typedef float f32x4  __attribute__((ext_vector_type(4)));

// ws float layout: [64..576) csq; [1024..17408) bf16 blob; [17408..19456) loss partials
#define WS_CSQ  64
#define WS_BLOB 1024
#define WS_PART 17408

static __device__ __forceinline__ unsigned short f2bf(float f) {
    union { float f; unsigned u; } v; v.f = f;
    unsigned u = v.u;
    return (unsigned short)((u + 0x7fffu + ((u >> 16) & 1u)) >> 16);  // RNE
}

// prep: exact fp32 csq, codebook -> bf16 fragment blob
// blob[((kt*2+f)*64 + l)*8 + j] = bf16(cw[kt*16 + (l&15)][f*32 + (l>>4)*8 + j])
__global__ void vq_prep_kernel(const float* __restrict__ cw, float* __restrict__ ws) {
    int tg = blockIdx.x * 256 + threadIdx.x;
    if (tg < KCW) {
        const float4* c4 = (const float4*)(cw + (size_t)tg * DIM);
        float s0 = 0.f, s1 = 0.f, s2 = 0.f, s3 = 0.f;
        #pragma unroll
        for (int i = 0; i < 16; ++i) {
            float4 c = c4[i];
            s0 = fmaf(c.x, c.x, s0); s1 = fmaf(c.y, c.y, s1);
            s2 = fmaf(c.z, c.z, s2); s3 = fmaf(c.w, c.w, s3);
        }
        ws[WS_CSQ + tg] = (s0 + s1) + (s2 + s3);
    }
    if (tg < 4096) {
        int l = tg & 63, f = (tg >> 6) & 1, kt = tg >> 7;
        int col = kt * 16 + (l & 15);
        unsigned short* blob = (unsigned short*)(ws + WS_BLOB);
        #pragma unroll
        for (int j = 0; j < 8; ++j) {
            int d = f * 32 + (l >> 4) * 8 + j;
            blob[((kt * 2 + f) * 64 + l) * 8 + j] = f2bf(cw[col * DIM + d]);
        }
    }
}

// One block = 64 rows x 512 codewords. 8 waves: wave w -> row-group (w&3),
// codebook half (w>>2). Two MFMA sweeps (min, then LDS-atomic candidate insert),
// exact fp32 refine (8 threads/row), per-block loss partial (no global atomic).
// unroll 2 on the sweeps: unroll 4 + the 64-VGPR bound spilled 160 B/thread (R8).
__global__ __launch_bounds__(512, 8)
void vq_main_kernel(const float* __restrict__ in, const float* __restrict__ cw,
                    const float* __restrict__ ws_ro, float* __restrict__ part,
                    float* __restrict__ out) {
    __shared__ __align__(16) float xl[DIM * XP];   // 17.4 KB fp32 x-tile [d][row]
    __shared__ unsigned short cand[64][CMAX];      // 2 KB
    __shared__ int   cnts[64];
    __shared__ float xsqa[64];
    __shared__ int   sidxl[64];
    __shared__ float mnh[64][2];                   // per-row min, per kt-half
    __shared__ float redf[8];
    __shared__ int   redk[8];
    __shared__ float lossb;

    const float*  __restrict__ csqg = ws_ro + WS_CSQ;
    const bf16x8* __restrict__ bp   = (const bf16x8*)(ws_ro + WS_BLOB);

    const int t  = threadIdx.x;
    const int w  = t >> 6, l = t & 63, g = l >> 4, cl = l & 15;
    const int h  = w >> 2;            // codebook half (kt 16h .. 16h+15)
    const int wr = w & 3;             // row-group (rows 16wr .. 16wr+15)
    const int b    = blockIdx.x >> 6;
    const int hw0  = (blockIdx.x & 63) * 64;
    const int row0 = blockIdx.x * 64;

    if (t < 64) cnts[t] = 0;
    if (t == 0) lossb = 0.f;

    // ---- stage x tile (single global read of this block's input)
    {
        const int tx = t & 15, ty = t >> 4;       // ty 0..31
        const float* __restrict__ xb = in + (size_t)b * (DIM * HWSZ) + hw0;
        #pragma unroll
        for (int p = 0; p < 2; ++p) {
            int d = p * 32 + ty;
            *(float4*)(xl + d * XP + tx * 4) = *(const float4*)(xb + (size_t)d * HWSZ + tx * 4);
        }
    }
    __syncthreads();

    // ---- exact ||x||^2: row t>>3, dim-eighth t&7, 8-lane shuffle reduce
    {
        int r = t >> 3, q = t & 7;
        float s = 0.f;
        #pragma unroll
        for (int i = 0; i < 8; ++i) {
            float xv = xl[(q * 8 + i) * XP + r];
            s = fmaf(xv, xv, s);
        }
        s += __shfl_xor(s, 1, 64);
        s += __shfl_xor(s, 2, 64);
        s += __shfl_xor(s, 4, 64);
        if (q == 0) xsqa[r] = s;                  // consumed after the mnh barrier
    }

    // ---- A fragments bf16(-x): row = wr*16+cl, d-slots by g
    const int myrow = wr * 16 + cl;
    bf16x8 a0, a1;
    #pragma unroll
    for (int j = 0; j < 8; ++j) a0[j] = (short)f2bf(-xl[(g * 8 + j) * XP + myrow]);
    #pragma unroll
    for (int j = 0; j < 8; ++j) a1[j] = (short)f2bf(-xl[(32 + g * 8 + j) * XP + myrow]);

    // ---- sweep 1: per-row min of score s = csq/2 - dot over this wave's 16 kt
    float mn[4] = {INFINITY, INFINITY, INFINITY, INFINITY};
    #pragma unroll 2
    for (int k2 = 0; k2 < 16; ++k2) {
        const int kt = h * 16 + k2;
        float ci = 0.5f * csqg[kt * 16 + cl];
        f32x4 acc = {ci, ci, ci, ci};
        bf16x8 b0 = bp[(kt * 2 + 0) * 64 + l];
        bf16x8 b1 = bp[(kt * 2 + 1) * 64 + l];
        acc = __builtin_amdgcn_mfma_f32_16x16x32_bf16(a0, b0, acc, 0, 0, 0);
        acc = __builtin_amdgcn_mfma_f32_16x16x32_bf16(a1, b1, acc, 0, 0, 0);
        #pragma unroll
        for (int rg = 0; rg < 4; ++rg) mn[rg] = fminf(mn[rg], acc[rg]);
    }
    #pragma unroll
    for (int off = 1; off < 16; off <<= 1)        // min over the 16 col-lanes
        #pragma unroll
        for (int rg = 0; rg < 4; ++rg)
            mn[rg] = fminf(mn[rg], __shfl_xor(mn[rg], off, 64));
    if (cl == 0) {
        #pragma unroll
        for (int rg = 0; rg < 4; ++rg) mnh[wr * 16 + 4 * g + rg][h] = mn[rg];
    }
    __syncthreads();

    // bound: 2*beta = ||x||/16 (bf16 u=2^-9, ||c||<=8) + 0.25 margin (R6/R7-proven)
    float thr[4];
    #pragma unroll
    for (int rg = 0; rg < 4; ++rg) {
        int r = wr * 16 + 4 * g + rg;
        float m = fminf(mnh[r][0], mnh[r][1]);
        thr[rg] = m + 0.0625f * sqrtf(xsqa[r]) + 0.25f;
    }

    // ---- sweep 2: recompute, insert candidates (order races; refine is lex-safe)
    #pragma unroll 2
    for (int k2 = 0; k2 < 16; ++k2) {
        const int kt = h * 16 + k2;
        float ci = 0.5f * csqg[kt * 16 + cl];
        f32x4 acc = {ci, ci, ci, ci};
        bf16x8 b0 = bp[(kt * 2 + 0) * 64 + l];
        bf16x8 b1 = bp[(kt * 2 + 1) * 64 + l];
        acc = __builtin_amdgcn_mfma_f32_16x16x32_bf16(a0, b0, acc, 0, 0, 0);
        acc = __builtin_amdgcn_mfma_f32_16x16x32_bf16(a1, b1, acc, 0, 0, 0);
        #pragma unroll
        for (int rg = 0; rg < 4; ++rg) {
            if (acc[rg] <= thr[rg]) {
                int r = wr * 16 + 4 * g + rg;
                int pos = atomicAdd(&cnts[r], 1);
                if (pos < CMAX) cand[r][pos] = (unsigned short)(kt * 16 + cl);
            }
        }
    }
    __syncthreads();

    // ---- exact fp32 refine: 8 slot-threads per row, lex (dist,k) tie-break
    {
        const int rr = t >> 3, slot = t & 7;
        const int n = cnts[rr];
        if (n <= CMAX) {                          // n >= 1 always (min qualifies)
            float bb = INFINITY; int bkk = 0x7fffffff;
            const float xsqe = xsqa[rr];
            for (int s = slot; s < n; s += 8) {
                int k = cand[rr][s];
                const float4* __restrict__ c4 = (const float4*)(cw + (size_t)k * DIM);
                float d0 = 0.f, d1 = 0.f, d2 = 0.f, d3 = 0.f;
                #pragma unroll
                for (int i = 0; i < 16; ++i) {
                    float4 c = c4[i];
                    d0 = fmaf(xl[(4 * i + 0) * XP + rr], c.x, d0);
                    d1 = fmaf(xl[(4 * i + 1) * XP + rr], c.y, d1);
                    d2 = fmaf(xl[(4 * i + 2) * XP + rr], c.z, d2);
                    d3 = fmaf(xl[(4 * i + 3) * XP + rr], c.w, d3);
                }
                float dot  = (d0 + d1) + (d2 + d3);
                float dist = (xsqe + csqg[k]) - 2.f * dot;   // reference rounding order
                if (dist < bb || (dist == bb && k < bkk)) { bb = dist; bkk = k; }
            }
            #pragma unroll
            for (int off = 1; off < 8; off <<= 1) {
                float ob = __shfl_xor(bb, off, 64);
                int   ok = __shfl_xor(bkk, off, 64);
                if (ob < bb || (ob == bb && ok < bkk)) { bb = ob; bkk = ok; }
            }
            if (slot == 0) {
                sidxl[rr] = bkk;
                out[(size_t)NROW * DIM + row0 + rr] = (float)bkk;
            }
        }
    }
    __syncthreads();

    // ---- rare overflow rows: one codeword per thread, block lex-argmin
    for (int r = 0; r < 64; ++r) {
        if (cnts[r] <= CMAX) continue;            // block-uniform
        const float xsqe = xsqa[r];
        const int k = t;                          // 512 threads = 512 codewords
        const float4* __restrict__ c4 = (const float4*)(cw + (size_t)k * DIM);
        float d0 = 0.f, d1 = 0.f, d2 = 0.f, d3 = 0.f;
        #pragma unroll
        for (int i = 0; i < 16; ++i) {
            float4 c = c4[i];
            d0 = fmaf(xl[(4 * i + 0) * XP + r], c.x, d0);
            d1 = fmaf(xl[(4 * i + 1) * XP + r], c.y, d1);
            d2 = fmaf(xl[(4 * i + 2) * XP + r], c.z, d2);
            d3 = fmaf(xl[(4 * i + 3) * XP + r], c.w, d3);
        }
        float dot = (d0 + d1) + (d2 + d3);
        float bb  = (xsqe + csqg[k]) - 2.f * dot;
        int  bkk  = k;
        #pragma unroll
        for (int off = 32; off; off >>= 1) {
            float ob = __shfl_down(bb, off, 64);
            int   ok = __shfl_down(bkk, off, 64);
            if (ob < bb || (ob == bb && ok < bkk)) { bb = ob; bkk = ok; }
        }
        if (l == 0) { redf[w] = bb; redk[w] = bkk; }
        __syncthreads();
        if (t == 0) {
            float fb = redf[0]; int fk = redk[0];
            for (int w2 = 1; w2 < 8; ++w2)
                if (redf[w2] < fb || (redf[w2] == fb && redk[w2] < fk)) { fb = redf[w2]; fk = redk[w2]; }
            sidxl[r] = fk;
            out[(size_t)NROW * DIM + row0 + r] = (float)fk;
        }
        __syncthreads();
    }

    // ---- epilogue: gather codeword, write quantized NCHW, loss partial
    {
        const int gr = t & 63, seg = t >> 6;      // seg wave-uniform (0..7), 8 dims each
        const int kwin = sidxl[gr];
        const float* __restrict__ qp = cw + (size_t)kwin * DIM + seg * 8;
        float* __restrict__ obase = out + (size_t)b * (DIM * HWSZ) + hw0 + gr;
        float lsum = 0.f;
        #pragma unroll
        for (int dd = 0; dd < 2; ++dd) {
            float4 q4 = *(const float4*)(qp + dd * 4);
            float qv[4] = {q4.x, q4.y, q4.z, q4.w};
            #pragma unroll
            for (int c = 0; c < 4; ++c) {
                int d = seg * 8 + dd * 4 + c;
                float xv = xl[d * XP + gr];
                obase[(size_t)d * HWSZ] = qv[c];
                float diff = qv[c] - xv;
                lsum = fmaf(diff, diff, lsum);
            }
        }
        #pragma unroll
        for (int off = 32; off; off >>= 1) lsum += __shfl_down(lsum, off, 64);
        if (l == 0) atomicAdd(&lossb, lsum);
    }
    __syncthreads();
    if (t == 0) part[blockIdx.x] = lossb;
}

__global__ void vq_finalize_kernel(const float* __restrict__ part, float* __restrict__ out) {
    __shared__ float wsum[4];
    const int t = threadIdx.x;
    float s = 0.f;
    #pragma unroll
    for (int i = 0; i < 8; ++i) s += part[t * 8 + i];   // fixed order: deterministic
    #pragma unroll
    for (int off = 32; off; off >>= 1) s += __shfl_down(s, off, 64);
    if ((t & 63) == 0) wsum[t >> 6] = s;
    __syncthreads();
    if (t == 0)
        out[(size_t)NROW * DIM + NROW] =
            1.25f * ((wsum[0] + wsum[1]) + (wsum[2] + wsum[3])) / (float)((size_t)NROW * DIM);
}

extern "C" void kernel_launch(void* const* d_in, const int* in_sizes, int n_in,
                              void* d_out, int out_size, void* d_ws, size_t ws_size,
                              hipStream_t stream) {
    const float* in = (const float*)d_in[0];
    const float* cw = (const float*)d_in[1];
    float* out = (float*)d_out;
    float* ws  = (float*)d_ws;

    hipLaunchKernelGGL(vq_prep_kernel, dim3(16), dim3(256), 0, stream, cw, ws);
    hipLaunchKernelGGL(vq_main_kernel, dim3(NROW / 64), dim3(512), 0, stream,
                       in, cw, ws, ws + WS_PART, out);
    hipLaunchKernelGGL(vq_finalize_kernel, dim3(1), dim3(256), 0, stream, ws + WS_PART, out);
}

// Round 10
// 104.540 us; speedup vs baseline: 2.0793x; 1.1470x over previous
//
#include <hip/hip_runtime.h>
#include <math.h>

#define HWSZ 4096   // 64*64
#define DIM  64
#define KCW  512
#define NROW 131072 // 32*4096
#define CMAX 16
#define XP   68     // x-tile pitch (floats)

typedef short bf16x8 __attribute__((ext_vector_type(8)));
typedef float f32x4  __attribute__((ext_vector_type(4)));

// ws float layout: [64..576) csq; [1024..17408) bf16 blob; [17408..19456) loss partials
#define WS_CSQ  64
#define WS_BLOB 1024
#define WS_PART 17408

static __device__ __forceinline__ unsigned short f2bf(float f) {
    union { float f; unsigned u; } v; v.f = f;
    unsigned u = v.u;
    return (unsigned short)((u + 0x7fffu + ((u >> 16) & 1u)) >> 16);  // RNE
}

// prep: exact fp32 csq, codebook -> bf16 fragment blob
// blob[((kt*2+f)*64 + l)*8 + j] = bf16(cw[kt*16 + (l&15)][f*32 + (l>>4)*8 + j])
__global__ void vq_prep_kernel(const float* __restrict__ cw, float* __restrict__ ws) {
    int tg = blockIdx.x * 256 + threadIdx.x;
    if (tg < KCW) {
        const float4* c4 = (const float4*)(cw + (size_t)tg * DIM);
        float s0 = 0.f, s1 = 0.f, s2 = 0.f, s3 = 0.f;
        #pragma unroll
        for (int i = 0; i < 16; ++i) {
            float4 c = c4[i];
            s0 = fmaf(c.x, c.x, s0); s1 = fmaf(c.y, c.y, s1);
            s2 = fmaf(c.z, c.z, s2); s3 = fmaf(c.w, c.w, s3);
        }
        ws[WS_CSQ + tg] = (s0 + s1) + (s2 + s3);
    }
    if (tg < 4096) {
        int l = tg & 63, f = (tg >> 6) & 1, kt = tg >> 7;
        int col = kt * 16 + (l & 15);
        unsigned short* blob = (unsigned short*)(ws + WS_BLOB);
        #pragma unroll
        for (int j = 0; j < 8; ++j) {
            int d = f * 32 + (l >> 4) * 8 + j;
            blob[((kt * 2 + f) * 64 + l) * 8 + j] = f2bf(cw[col * DIM + d]);
        }
    }
}

// One block = 64 rows x 512 codewords. 8 waves: wave w -> row-group (w&3),
// codebook half (w>>2). Two MFMA sweeps (min, then LDS-atomic candidate insert),
// exact fp32 refine (8 threads/row), per-block loss partial (no global atomic).
// launch_bounds (512,4): the (512,8) 64-reg budget made the allocator (with the
// MFMA AGPR split) crush to 32 arch VGPRs and spill ~250 B/thread to scratch,
// which thrashed L2 -> 150 MB/dispatch of HBM traffic (R8/R9 counters).
__global__ __launch_bounds__(512, 4)
void vq_main_kernel(const float* __restrict__ in, const float* __restrict__ cw,
                    const float* __restrict__ ws_ro, float* __restrict__ part,
                    float* __restrict__ out) {
    __shared__ __align__(16) float xl[DIM * XP];   // 17.4 KB fp32 x-tile [d][row]
    __shared__ unsigned short cand[64][CMAX];      // 2 KB
    __shared__ int   cnts[64];
    __shared__ float xsqa[64];
    __shared__ int   sidxl[64];
    __shared__ float mnh[64][2];                   // per-row min, per kt-half
    __shared__ float redf[8];
    __shared__ int   redk[8];
    __shared__ float lossb;

    const float*  __restrict__ csqg = ws_ro + WS_CSQ;
    const bf16x8* __restrict__ bp   = (const bf16x8*)(ws_ro + WS_BLOB);

    const int t  = threadIdx.x;
    const int w  = t >> 6, l = t & 63, g = l >> 4, cl = l & 15;
    const int h  = w >> 2;            // codebook half (kt 16h .. 16h+15)
    const int wr = w & 3;             // row-group (rows 16wr .. 16wr+15)
    const int b    = blockIdx.x >> 6;
    const int hw0  = (blockIdx.x & 63) * 64;
    const int row0 = blockIdx.x * 64;

    if (t < 64) cnts[t] = 0;
    if (t == 0) lossb = 0.f;

    // ---- stage x tile (single global read of this block's input)
    {
        const int tx = t & 15, ty = t >> 4;       // ty 0..31
        const float* __restrict__ xb = in + (size_t)b * (DIM * HWSZ) + hw0;
        #pragma unroll
        for (int p = 0; p < 2; ++p) {
            int d = p * 32 + ty;
            *(float4*)(xl + d * XP + tx * 4) = *(const float4*)(xb + (size_t)d * HWSZ + tx * 4);
        }
    }
    __syncthreads();

    // ---- exact ||x||^2: row t>>3, dim-eighth t&7, 8-lane shuffle reduce
    {
        int r = t >> 3, q = t & 7;
        float s = 0.f;
        #pragma unroll
        for (int i = 0; i < 8; ++i) {
            float xv = xl[(q * 8 + i) * XP + r];
            s = fmaf(xv, xv, s);
        }
        s += __shfl_xor(s, 1, 64);
        s += __shfl_xor(s, 2, 64);
        s += __shfl_xor(s, 4, 64);
        if (q == 0) xsqa[r] = s;                  // consumed after the mnh barrier
    }

    // ---- A fragments bf16(-x): row = wr*16+cl, d-slots by g
    const int myrow = wr * 16 + cl;
    bf16x8 a0, a1;
    #pragma unroll
    for (int j = 0; j < 8; ++j) a0[j] = (short)f2bf(-xl[(g * 8 + j) * XP + myrow]);
    #pragma unroll
    for (int j = 0; j < 8; ++j) a1[j] = (short)f2bf(-xl[(32 + g * 8 + j) * XP + myrow]);

    // ---- sweep 1: per-row min of score s = csq/2 - dot over this wave's 16 kt
    float mn[4] = {INFINITY, INFINITY, INFINITY, INFINITY};
    #pragma unroll 2
    for (int k2 = 0; k2 < 16; ++k2) {
        const int kt = h * 16 + k2;
        float ci = 0.5f * csqg[kt * 16 + cl];
        f32x4 acc = {ci, ci, ci, ci};
        bf16x8 b0 = bp[(kt * 2 + 0) * 64 + l];
        bf16x8 b1 = bp[(kt * 2 + 1) * 64 + l];
        acc = __builtin_amdgcn_mfma_f32_16x16x32_bf16(a0, b0, acc, 0, 0, 0);
        acc = __builtin_amdgcn_mfma_f32_16x16x32_bf16(a1, b1, acc, 0, 0, 0);
        #pragma unroll
        for (int rg = 0; rg < 4; ++rg) mn[rg] = fminf(mn[rg], acc[rg]);
    }
    #pragma unroll
    for (int off = 1; off < 16; off <<= 1)        // min over the 16 col-lanes
        #pragma unroll
        for (int rg = 0; rg < 4; ++rg)
            mn[rg] = fminf(mn[rg], __shfl_xor(mn[rg], off, 64));
    if (cl == 0) {
        #pragma unroll
        for (int rg = 0; rg < 4; ++rg) mnh[wr * 16 + 4 * g + rg][h] = mn[rg];
    }
    __syncthreads();

    // bound: 2*beta = ||x||/16 (bf16 u=2^-9, ||c||<=8) + 0.25 margin (R6/R7-proven)
    float thr[4];
    #pragma unroll
    for (int rg = 0; rg < 4; ++rg) {
        int r = wr * 16 + 4 * g + rg;
        float m = fminf(mnh[r][0], mnh[r][1]);
        thr[rg] = m + 0.0625f * sqrtf(xsqa[r]) + 0.25f;
    }

    // ---- sweep 2: recompute, insert candidates (order races; refine is lex-safe)
    #pragma unroll 2
    for (int k2 = 0; k2 < 16; ++k2) {
        const int kt = h * 16 + k2;
        float ci = 0.5f * csqg[kt * 16 + cl];
        f32x4 acc = {ci, ci, ci, ci};
        bf16x8 b0 = bp[(kt * 2 + 0) * 64 + l];
        bf16x8 b1 = bp[(kt * 2 + 1) * 64 + l];
        acc = __builtin_amdgcn_mfma_f32_16x16x32_bf16(a0, b0, acc, 0, 0, 0);
        acc = __builtin_amdgcn_mfma_f32_16x16x32_bf16(a1, b1, acc, 0, 0, 0);
        #pragma unroll
        for (int rg = 0; rg < 4; ++rg) {
            if (acc[rg] <= thr[rg]) {
                int r = wr * 16 + 4 * g + rg;
                int pos = atomicAdd(&cnts[r], 1);
                if (pos < CMAX) cand[r][pos] = (unsigned short)(kt * 16 + cl);
            }
        }
    }
    __syncthreads();

    // ---- exact fp32 refine: 8 slot-threads per row, lex (dist,k) tie-break
    {
        const int rr = t >> 3, slot = t & 7;
        const int n = cnts[rr];
        if (n <= CMAX) {                          // n >= 1 always (min qualifies)
            float bb = INFINITY; int bkk = 0x7fffffff;
            const float xsqe = xsqa[rr];
            for (int s = slot; s < n; s += 8) {
                int k = cand[rr][s];
                const float4* __restrict__ c4 = (const float4*)(cw + (size_t)k * DIM);
                float d0 = 0.f, d1 = 0.f, d2 = 0.f, d3 = 0.f;
                #pragma unroll
                for (int i = 0; i < 16; ++i) {
                    float4 c = c4[i];
                    d0 = fmaf(xl[(4 * i + 0) * XP + rr], c.x, d0);
                    d1 = fmaf(xl[(4 * i + 1) * XP + rr], c.y, d1);
                    d2 = fmaf(xl[(4 * i + 2) * XP + rr], c.z, d2);
                    d3 = fmaf(xl[(4 * i + 3) * XP + rr], c.w, d3);
                }
                float dot  = (d0 + d1) + (d2 + d3);
                float dist = (xsqe + csqg[k]) - 2.f * dot;   // reference rounding order
                if (dist < bb || (dist == bb && k < bkk)) { bb = dist; bkk = k; }
            }
            #pragma unroll
            for (int off = 1; off < 8; off <<= 1) {
                float ob = __shfl_xor(bb, off, 64);
                int   ok = __shfl_xor(bkk, off, 64);
                if (ob < bb || (ob == bb && ok < bkk)) { bb = ob; bkk = ok; }
            }
            if (slot == 0) {
                sidxl[rr] = bkk;
                out[(size_t)NROW * DIM + row0 + rr] = (float)bkk;
            }
        }
    }
    __syncthreads();

    // ---- rare overflow rows: one codeword per thread, block lex-argmin
    for (int r = 0; r < 64; ++r) {
        if (cnts[r] <= CMAX) continue;            // block-uniform
        const float xsqe = xsqa[r];
        const int k = t;                          // 512 threads = 512 codewords
        const float4* __restrict__ c4 = (const float4*)(cw + (size_t)k * DIM);
        float d0 = 0.f, d1 = 0.f, d2 = 0.f, d3 = 0.f;
        #pragma unroll
        for (int i = 0; i < 16; ++i) {
            float4 c = c4[i];
            d0 = fmaf(xl[(4 * i + 0) * XP + r], c.x, d0);
            d1 = fmaf(xl[(4 * i + 1) * XP + r], c.y, d1);
            d2 = fmaf(xl[(4 * i + 2) * XP + r], c.z, d2);
            d3 = fmaf(xl[(4 * i + 3) * XP + r], c.w, d3);
        }
        float dot = (d0 + d1) + (d2 + d3);
        float bb  = (xsqe + csqg[k]) - 2.f * dot;
        int  bkk  = k;
        #pragma unroll
        for (int off = 32; off; off >>= 1) {
            float ob = __shfl_down(bb, off, 64);
            int   ok = __shfl_down(bkk, off, 64);
            if (ob < bb || (ob == bb && ok < bkk)) { bb = ob; bkk = ok; }
        }
        if (l == 0) { redf[w] = bb; redk[w] = bkk; }
        __syncthreads();
        if (t == 0) {
            float fb = redf[0]; int fk = redk[0];
            for (int w2 = 1; w2 < 8; ++w2)
                if (redf[w2] < fb || (redf[w2] == fb && redk[w2] < fk)) { fb = redf[w2]; fk = redk[w2]; }
            sidxl[r] = fk;
            out[(size_t)NROW * DIM + row0 + r] = (float)fk;
        }
        __syncthreads();
    }

    // ---- epilogue: gather codeword, write quantized NCHW, loss partial
    {
        const int gr = t & 63, seg = t >> 6;      // seg wave-uniform (0..7), 8 dims each
        const int kwin = sidxl[gr];
        const float* __restrict__ qp = cw + (size_t)kwin * DIM + seg * 8;
        float* __restrict__ obase = out + (size_t)b * (DIM * HWSZ) + hw0 + gr;
        float lsum = 0.f;
        #pragma unroll
        for (int dd = 0; dd < 2; ++dd) {
            float4 q4 = *(const float4*)(qp + dd * 4);
            float qv[4] = {q4.x, q4.y, q4.z, q4.w};
            #pragma unroll
            for (int c = 0; c < 4; ++c) {
                int d = seg * 8 + dd * 4 + c;
                float xv = xl[d * XP + gr];
                obase[(size_t)d * HWSZ] = qv[c];
                float diff = qv[c] - xv;
                lsum = fmaf(diff, diff, lsum);
            }
        }
        #pragma unroll
        for (int off = 32; off; off >>= 1) lsum += __shfl_down(lsum, off, 64);
        if (l == 0) atomicAdd(&lossb, lsum);
    }
    __syncthreads();
    if (t == 0) part[blockIdx.x] = lossb;
}

__global__ void vq_finalize_kernel(const float* __restrict__ part, float* __restrict__ out) {
    __shared__ float wsum[4];
    const int t = threadIdx.x;
    float s = 0.f;
    #pragma unroll
    for (int i = 0; i < 8; ++i) s += part[t * 8 + i];   // fixed order: deterministic
    #pragma unroll
    for (int off = 32; off; off >>= 1) s += __shfl_down(s, off, 64);
    if ((t & 63) == 0) wsum[t >> 6] = s;
    __syncthreads();
    if (t == 0)
        out[(size_t)NROW * DIM + NROW] =
            1.25f * ((wsum[0] + wsum[1]) + (wsum[2] + wsum[3])) / (float)((size_t)NROW * DIM);
}

extern "C" void kernel_launch(void* const* d_in, const int* in_sizes, int n_in,
                              void* d_out, int out_size, void* d_ws, size_t ws_size,
                              hipStream_t stream) {
    const float* in = (const float*)d_in[0];
    const float* cw = (const float*)d_in[1];
    float* out = (float*)d_out;
    float* ws  = (float*)d_ws;

    hipLaunchKernelGGL(vq_prep_kernel, dim3(16), dim3(256), 0, stream, cw, ws);
    hipLaunchKernelGGL(vq_main_kernel, dim3(NROW / 64), dim3(512), 0, stream,
                       in, cw, ws, ws + WS_PART, out);
    hipLaunchKernelGGL(vq_finalize_kernel, dim3(1), dim3(256), 0, stream, ws + WS_PART, out);
}

// Round 11
// 91.654 us; speedup vs baseline: 2.3717x; 1.1406x over previous
//
#include <hip/hip_runtime.h>
#include <math.h>

#define HWSZ 4096   // 64*64
#define DIM  64
#define KCW  512
#define NROW 131072 // 32*4096
#define CMAX 16

typedef short bf16x8 __attribute__((ext_vector_type(8)));
typedef float f32x4  __attribute__((ext_vector_type(4)));

// ws float layout: [64..576) csq; [1024..17408) bf16 blob; [17408..19456) loss partials
#define WS_CSQ  64
#define WS_BLOB 1024
#define WS_PART 17408

static __device__ __forceinline__ unsigned short f2bf(float f) {
    union { float f; unsigned u; } v; v.f = f;
    unsigned u = v.u;
    return (unsigned short)((u + 0x7fffu + ((u >> 16) & 1u)) >> 16);  // RNE
}

// prep: exact fp32 csq, codebook -> bf16 fragment blob
// blob[((kt*2+f)*64 + l)*8 + j] = bf16(cw[kt*16 + (l&15)][f*32 + (l>>4)*8 + j])
__global__ void vq_prep_kernel(const float* __restrict__ cw, float* __restrict__ ws) {
    int tg = blockIdx.x * 256 + threadIdx.x;
    if (tg < KCW) {
        const float4* c4 = (const float4*)(cw + (size_t)tg * DIM);
        float s0 = 0.f, s1 = 0.f, s2 = 0.f, s3 = 0.f;
        #pragma unroll
        for (int i = 0; i < 16; ++i) {
            float4 c = c4[i];
            s0 = fmaf(c.x, c.x, s0); s1 = fmaf(c.y, c.y, s1);
            s2 = fmaf(c.z, c.z, s2); s3 = fmaf(c.w, c.w, s3);
        }
        ws[WS_CSQ + tg] = (s0 + s1) + (s2 + s3);
    }
    if (tg < 4096) {
        int l = tg & 63, f = (tg >> 6) & 1, kt = tg >> 7;
        int col = kt * 16 + (l & 15);
        unsigned short* blob = (unsigned short*)(ws + WS_BLOB);
        #pragma unroll
        for (int j = 0; j < 8; ++j) {
            int d = f * 32 + (l >> 4) * 8 + j;
            blob[((kt * 2 + f) * 64 + l) * 8 + j] = f2bf(cw[col * DIM + d]);
        }
    }
}

// One block = 64 rows x 512 codewords. 8 waves: wave w -> row-group (w&3),
// codebook half (w>>2). The 64 KB bf16 codebook blob + csq are staged in LDS
// once per block (R10's sweeps streamed ~1 GB/dispatch of the blob through L2
// at ~200cy/hit -- that latency chain was the 104 us floor). x is read from
// global: A-frag build once, refine/epilogue re-read L2-hot.
__global__ __launch_bounds__(512, 4)
void vq_main_kernel(const float* __restrict__ in, const float* __restrict__ cw,
                    const float* __restrict__ ws_ro, float* __restrict__ part,
                    float* __restrict__ out) {
    __shared__ __align__(16) unsigned short blob_l[4096 * 8];  // 64 KB
    __shared__ float csq_l[KCW];                               // 2 KB
    __shared__ unsigned short cand[64][CMAX];                  // 2 KB
    __shared__ int   cnts[64];
    __shared__ float xsqa[64];
    __shared__ int   sidxl[64];
    __shared__ float mnh[64][2];                               // per-row min, per kt-half
    __shared__ float redf[8];
    __shared__ int   redk[8];
    __shared__ float lossb;

    const int t  = threadIdx.x;
    const int w  = t >> 6, l = t & 63, g = l >> 4, cl = l & 15;
    const int h  = w >> 2;            // codebook half (kt 16h .. 16h+15)
    const int wr = w & 3;             // row-group (rows 16wr .. 16wr+15)
    const int b    = blockIdx.x >> 6;
    const int hw0  = (blockIdx.x & 63) * 64;
    const int row0 = blockIdx.x * 64;

    // ---- stage codebook blob + csq into LDS (one global read per block)
    {
        const float4* __restrict__ bg = (const float4*)(ws_ro + WS_BLOB);
        float4* bl4 = (float4*)blob_l;
        #pragma unroll
        for (int i = 0; i < 8; ++i) bl4[i * 512 + t] = bg[i * 512 + t];
        csq_l[t] = ws_ro[WS_CSQ + t];
    }
    if (t < 64) cnts[t] = 0;
    if (t == 0) lossb = 0.f;

    // ---- A fragments bf16(-x) + exact ||x||^2, straight from global
    const int myrow = wr * 16 + cl;
    const float* __restrict__ xb = in + (size_t)b * (DIM * HWSZ) + hw0 + myrow;
    bf16x8 a0, a1;
    float xs_p = 0.f;
    #pragma unroll
    for (int j = 0; j < 8; ++j) {
        float xv = xb[(size_t)(g * 8 + j) * HWSZ];
        xs_p = fmaf(xv, xv, xs_p);
        a0[j] = (short)f2bf(-xv);
    }
    #pragma unroll
    for (int j = 0; j < 8; ++j) {
        float xv = xb[(size_t)(32 + g * 8 + j) * HWSZ];
        xs_p = fmaf(xv, xv, xs_p);
        a1[j] = (short)f2bf(-xv);
    }
    xs_p += __shfl_xor(xs_p, 16, 64);          // combine the 4 d-groups of this row
    xs_p += __shfl_xor(xs_p, 32, 64);
    if (h == 0 && g == 0) xsqa[myrow] = xs_p;  // one writer per row
    __syncthreads();                           // blob_l / csq_l / xsqa ready

    const bf16x8* __restrict__ bls = (const bf16x8*)blob_l;

    // ---- sweep 1: per-row min of score s = csq/2 - dot over this wave's 16 kt
    float mn[4] = {INFINITY, INFINITY, INFINITY, INFINITY};
    #pragma unroll 2
    for (int k2 = 0; k2 < 16; ++k2) {
        const int kt = h * 16 + k2;
        float ci = 0.5f * csq_l[kt * 16 + cl];
        f32x4 acc = {ci, ci, ci, ci};
        bf16x8 b0 = bls[(kt * 2 + 0) * 64 + l];
        bf16x8 b1 = bls[(kt * 2 + 1) * 64 + l];
        acc = __builtin_amdgcn_mfma_f32_16x16x32_bf16(a0, b0, acc, 0, 0, 0);
        acc = __builtin_amdgcn_mfma_f32_16x16x32_bf16(a1, b1, acc, 0, 0, 0);
        #pragma unroll
        for (int rg = 0; rg < 4; ++rg) mn[rg] = fminf(mn[rg], acc[rg]);
    }
    #pragma unroll
    for (int off = 1; off < 16; off <<= 1)     // min over the 16 col-lanes
        #pragma unroll
        for (int rg = 0; rg < 4; ++rg)
            mn[rg] = fminf(mn[rg], __shfl_xor(mn[rg], off, 64));
    if (cl == 0) {
        #pragma unroll
        for (int rg = 0; rg < 4; ++rg) mnh[wr * 16 + 4 * g + rg][h] = mn[rg];
    }
    __syncthreads();

    // bound: 2*beta = ||x||/16 (bf16 u=2^-9, ||c||<=8) + 0.25 margin (R6-R10 proven)
    float thr[4];
    #pragma unroll
    for (int rg = 0; rg < 4; ++rg) {
        int r = wr * 16 + 4 * g + rg;
        float m = fminf(mnh[r][0], mnh[r][1]);
        thr[rg] = m + 0.0625f * sqrtf(xsqa[r]) + 0.25f;
    }

    // ---- sweep 2: recompute, insert candidates (order races; refine is lex-safe)
    #pragma unroll 2
    for (int k2 = 0; k2 < 16; ++k2) {
        const int kt = h * 16 + k2;
        float ci = 0.5f * csq_l[kt * 16 + cl];
        f32x4 acc = {ci, ci, ci, ci};
        bf16x8 b0 = bls[(kt * 2 + 0) * 64 + l];
        bf16x8 b1 = bls[(kt * 2 + 1) * 64 + l];
        acc = __builtin_amdgcn_mfma_f32_16x16x32_bf16(a0, b0, acc, 0, 0, 0);
        acc = __builtin_amdgcn_mfma_f32_16x16x32_bf16(a1, b1, acc, 0, 0, 0);
        #pragma unroll
        for (int rg = 0; rg < 4; ++rg) {
            if (acc[rg] <= thr[rg]) {
                int r = wr * 16 + 4 * g + rg;
                int pos = atomicAdd(&cnts[r], 1);
                if (pos < CMAX) cand[r][pos] = (unsigned short)(kt * 16 + cl);
            }
        }
    }
    __syncthreads();

    // ---- exact fp32 refine: 8 slot-threads per row, x from global (L2-hot)
    {
        const int rr = t >> 3, slot = t & 7;
        const int n = cnts[rr];
        const float* __restrict__ xr = in + (size_t)b * (DIM * HWSZ) + hw0 + rr;
        if (n <= CMAX) {                          // n >= 1 always (min qualifies)
            float bb = INFINITY; int bkk = 0x7fffffff;
            const float xsqe = xsqa[rr];
            for (int s = slot; s < n; s += 8) {
                int k = cand[rr][s];
                const float4* __restrict__ c4 = (const float4*)(cw + (size_t)k * DIM);
                float d0 = 0.f, d1 = 0.f, d2 = 0.f, d3 = 0.f;
                #pragma unroll
                for (int i = 0; i < 16; ++i) {
                    float4 c = c4[i];
                    d0 = fmaf(xr[(size_t)(4 * i + 0) * HWSZ], c.x, d0);
                    d1 = fmaf(xr[(size_t)(4 * i + 1) * HWSZ], c.y, d1);
                    d2 = fmaf(xr[(size_t)(4 * i + 2) * HWSZ], c.z, d2);
                    d3 = fmaf(xr[(size_t)(4 * i + 3) * HWSZ], c.w, d3);
                }
                float dot  = (d0 + d1) + (d2 + d3);
                float dist = (xsqe + csq_l[k]) - 2.f * dot;  // reference rounding order
                if (dist < bb || (dist == bb && k < bkk)) { bb = dist; bkk = k; }
            }
            #pragma unroll
            for (int off = 1; off < 8; off <<= 1) {
                float ob = __shfl_xor(bb, off, 64);
                int   ok = __shfl_xor(bkk, off, 64);
                if (ob < bb || (ob == bb && ok < bkk)) { bb = ob; bkk = ok; }
            }
            if (slot == 0) {
                sidxl[rr] = bkk;
                out[(size_t)NROW * DIM + row0 + rr] = (float)bkk;
            }
        }
    }
    __syncthreads();

    // ---- rare overflow rows: one codeword per thread, block lex-argmin
    for (int r = 0; r < 64; ++r) {
        if (cnts[r] <= CMAX) continue;            // block-uniform
        const float xsqe = xsqa[r];
        const float* __restrict__ xr2 = in + (size_t)b * (DIM * HWSZ) + hw0 + r;
        const int k = t;                          // 512 threads = 512 codewords
        const float4* __restrict__ c4 = (const float4*)(cw + (size_t)k * DIM);
        float d0 = 0.f, d1 = 0.f, d2 = 0.f, d3 = 0.f;
        #pragma unroll
        for (int i = 0; i < 16; ++i) {
            float4 c = c4[i];
            d0 = fmaf(xr2[(size_t)(4 * i + 0) * HWSZ], c.x, d0);
            d1 = fmaf(xr2[(size_t)(4 * i + 1) * HWSZ], c.y, d1);
            d2 = fmaf(xr2[(size_t)(4 * i + 2) * HWSZ], c.z, d2);
            d3 = fmaf(xr2[(size_t)(4 * i + 3) * HWSZ], c.w, d3);
        }
        float dot = (d0 + d1) + (d2 + d3);
        float bb  = (xsqe + csq_l[k]) - 2.f * dot;
        int  bkk  = k;
        #pragma unroll
        for (int off = 32; off; off >>= 1) {
            float ob = __shfl_down(bb, off, 64);
            int   ok = __shfl_down(bkk, off, 64);
            if (ob < bb || (ob == bb && ok < bkk)) { bb = ob; bkk = ok; }
        }
        if (l == 0) { redf[w] = bb; redk[w] = bkk; }
        __syncthreads();
        if (t == 0) {
            float fb = redf[0]; int fk = redk[0];
            for (int w2 = 1; w2 < 8; ++w2)
                if (redf[w2] < fb || (redf[w2] == fb && redk[w2] < fk)) { fb = redf[w2]; fk = redk[w2]; }
            sidxl[r] = fk;
            out[(size_t)NROW * DIM + row0 + r] = (float)fk;
        }
        __syncthreads();
    }

    // ---- epilogue: gather codeword, write quantized NCHW, loss partial
    {
        const int gr = t & 63, seg = t >> 6;      // seg wave-uniform (0..7), 8 dims each
        const int kwin = sidxl[gr];
        const float* __restrict__ qp = cw + (size_t)kwin * DIM + seg * 8;
        const float* __restrict__ xe = in + (size_t)b * (DIM * HWSZ) + hw0 + gr;
        float* __restrict__ obase = out + (size_t)b * (DIM * HWSZ) + hw0 + gr;
        float lsum = 0.f;
        #pragma unroll
        for (int dd = 0; dd < 2; ++dd) {
            float4 q4 = *(const float4*)(qp + dd * 4);
            float qv[4] = {q4.x, q4.y, q4.z, q4.w};
            #pragma unroll
            for (int c = 0; c < 4; ++c) {
                int d = seg * 8 + dd * 4 + c;
                float xv = xe[(size_t)d * HWSZ];  // coalesced across gr, L2-hot
                obase[(size_t)d * HWSZ] = qv[c];
                float diff = qv[c] - xv;
                lsum = fmaf(diff, diff, lsum);
            }
        }
        #pragma unroll
        for (int off = 32; off; off >>= 1) lsum += __shfl_down(lsum, off, 64);
        if (l == 0) atomicAdd(&lossb, lsum);
    }
    __syncthreads();
    if (t == 0) part[blockIdx.x] = lossb;
}

__global__ void vq_finalize_kernel(const float* __restrict__ part, float* __restrict__ out) {
    __shared__ float wsum[4];
    const int t = threadIdx.x;
    float s = 0.f;
    #pragma unroll
    for (int i = 0; i < 8; ++i) s += part[t * 8 + i];   // fixed order: deterministic
    #pragma unroll
    for (int off = 32; off; off >>= 1) s += __shfl_down(s, off, 64);
    if ((t & 63) == 0) wsum[t >> 6] = s;
    __syncthreads();
    if (t == 0)
        out[(size_t)NROW * DIM + NROW] =
            1.25f * ((wsum[0] + wsum[1]) + (wsum[2] + wsum[3])) / (float)((size_t)NROW * DIM);
}

extern "C" void kernel_launch(void* const* d_in, const int* in_sizes, int n_in,
                              void* d_out, int out_size, void* d_ws, size_t ws_size,
                              hipStream_t stream) {
    const float* in = (const float*)d_in[0];
    const float* cw = (const float*)d_in[1];
    float* out = (float*)d_out;
    float* ws  = (float*)d_ws;

    hipLaunchKernelGGL(vq_prep_kernel, dim3(16), dim3(256), 0, stream, cw, ws);
    hipLaunchKernelGGL(vq_main_kernel, dim3(NROW / 64), dim3(512), 0, stream,
                       in, cw, ws, ws + WS_PART, out);
    hipLaunchKernelGGL(vq_finalize_kernel, dim3(1), dim3(256), 0, stream, ws + WS_PART, out);
}

// Round 12
// 88.074 us; speedup vs baseline: 2.4681x; 1.0407x over previous
//
#include <hip/hip_runtime.h>
#include <math.h>

#define HWSZ 4096   // 64*64
#define DIM  64
#define KCW  512
#define NROW 131072 // 32*4096
#define CMAX 16
#define XP   68     // x-tile pitch (floats)

typedef short bf16x8 __attribute__((ext_vector_type(8)));
typedef float f32x4  __attribute__((ext_vector_type(4)));

// ws float layout: [64..576) csq; [1024..17408) bf16 blob; [17408..19456) loss partials
#define WS_CSQ  64
#define WS_BLOB 1024
#define WS_PART 17408

static __device__ __forceinline__ unsigned short f2bf(float f) {
    union { float f; unsigned u; } v; v.f = f;
    unsigned u = v.u;
    return (unsigned short)((u + 0x7fffu + ((u >> 16) & 1u)) >> 16);  // RNE
}

// prep: exact fp32 csq, codebook -> bf16 fragment blob
// blob[((kt*2+f)*64 + l)*8 + j] = bf16(cw[kt*16 + (l&15)][f*32 + (l>>4)*8 + j])
__global__ void vq_prep_kernel(const float* __restrict__ cw, float* __restrict__ ws) {
    int tg = blockIdx.x * 256 + threadIdx.x;
    if (tg < KCW) {
        const float4* c4 = (const float4*)(cw + (size_t)tg * DIM);
        float s0 = 0.f, s1 = 0.f, s2 = 0.f, s3 = 0.f;
        #pragma unroll
        for (int i = 0; i < 16; ++i) {
            float4 c = c4[i];
            s0 = fmaf(c.x, c.x, s0); s1 = fmaf(c.y, c.y, s1);
            s2 = fmaf(c.z, c.z, s2); s3 = fmaf(c.w, c.w, s3);
        }
        ws[WS_CSQ + tg] = (s0 + s1) + (s2 + s3);
    }
    if (tg < 4096) {
        int l = tg & 63, f = (tg >> 6) & 1, kt = tg >> 7;
        int col = kt * 16 + (l & 15);
        unsigned short* blob = (unsigned short*)(ws + WS_BLOB);
        #pragma unroll
        for (int j = 0; j < 8; ++j) {
            int d = f * 32 + (l >> 4) * 8 + j;
            blob[((kt * 2 + f) * 64 + l) * 8 + j] = f2bf(cw[col * DIM + d]);
        }
    }
}

// One block = 64 rows x 512 codewords, 8 waves. Wave w holds codeword tiles
// kt=4w..4w+3 (64 cols) in REGISTERS (B-frags, loaded once from the global
// blob). Per 16-row group: 2 ds_read of shared bf16 A-frags + 8 MFMA; scores
// stay in regs -> after cross-wave min (LDS minw + barrier) candidates are
// selected by comparing the HELD accs (no second sweep at all -- R11's
// recompute sweep was ~40% of its VALU+MFMA). x lives in a 17 KB LDS tile:
// af-build, refine and epilogue are LDS-local; global x is read exactly once.
__global__ __launch_bounds__(512, 4)
void vq_main_kernel(const float* __restrict__ in, const float* __restrict__ cw,
                    const float* __restrict__ ws_ro, float* __restrict__ part,
                    float* __restrict__ out) {
    __shared__ __align__(16) float xl[DIM * XP];          // 17.4 KB fp32 x-tile [d][row]
    __shared__ __align__(16) unsigned short af[8 * 64 * 8]; // 8 KB bf16 A-frags [(g*2+f)*64+l][8]
    __shared__ float csq_l[KCW];                          // 2 KB
    __shared__ unsigned short cand[64][CMAX];             // 2 KB
    __shared__ int   cnts[64];
    __shared__ float xsqa[64];
    __shared__ float marg[64];                            // 0.0625*sqrt(xsq)+0.25
    __shared__ int   sidxl[64];
    __shared__ float minw[16][8];                         // per-group row-min per wave
    __shared__ float thrA[16];
    __shared__ float redf[8];
    __shared__ int   redk[8];
    __shared__ float lossb;

    const int t  = threadIdx.x;
    const int w  = t >> 6, l = t & 63, g4 = l >> 4, cl = l & 15;
    const int b    = blockIdx.x >> 6;
    const int hw0  = (blockIdx.x & 63) * 64;
    const int row0 = blockIdx.x * 64;

    // ---- B-fragments for this wave's 4 kt-tiles: straight global->regs (L2-hot)
    const bf16x8* __restrict__ bp = (const bf16x8*)(ws_ro + WS_BLOB);
    bf16x8 bw0[4], bw1[4];
    #pragma unroll
    for (int kt4 = 0; kt4 < 4; ++kt4) {
        const int kt = 4 * w + kt4;
        bw0[kt4] = bp[(kt * 2 + 0) * 64 + l];
        bw1[kt4] = bp[(kt * 2 + 1) * 64 + l];
    }

    // ---- stage x tile (coalesced, the only global read of x) + csq
    {
        const int tx = t & 15, ty = t >> 4;               // ty 0..31
        const float* __restrict__ xb = in + (size_t)b * (DIM * HWSZ) + hw0;
        #pragma unroll
        for (int p = 0; p < 2; ++p) {
            int d = p * 32 + ty;
            *(float4*)(xl + d * XP + tx * 4) = *(const float4*)(xb + (size_t)d * HWSZ + tx * 4);
        }
    }
    csq_l[t] = ws_ro[WS_CSQ + t];
    if (t < 64) cnts[t] = 0;
    if (t == 0) lossb = 0.f;
    __syncthreads();                                      // xl, csq ready

    // ---- exact ||x||^2 + threshold margin (once per row)
    {
        int r = t >> 3, q = t & 7;
        float s = 0.f;
        #pragma unroll
        for (int i = 0; i < 8; ++i) {
            float xv = xl[(q * 8 + i) * XP + r];
            s = fmaf(xv, xv, s);
        }
        s += __shfl_xor(s, 1, 64);
        s += __shfl_xor(s, 2, 64);
        s += __shfl_xor(s, 4, 64);
        if (q == 0) { xsqa[r] = s; marg[r] = 0.0625f * sqrtf(s) + 0.25f; }
    }

    // ---- build shared bf16 A-fragments ONCE (R11 built them 8x, per wave):
    // chunk t: gf=t>>6 (g=gf>>1, f=gf&1), la=t&63; row=g*16+(la&15), d=f*32+(la>>4)*8+j
    {
        const int gf = t >> 6, la = t & 63;
        const int row = (gf >> 1) * 16 + (la & 15);
        const int db  = (gf & 1) * 32 + (la >> 4) * 8;
        bf16x8 tmp;
        #pragma unroll
        for (int j = 0; j < 8; ++j) tmp[j] = (short)f2bf(-xl[(db + j) * XP + row]);
        *(bf16x8*)(af + t * 8) = tmp;
    }
    __syncthreads();                                      // af, xsqa, marg ready

    const bf16x8* __restrict__ afp = (const bf16x8*)af;
    float ci[4];
    #pragma unroll
    for (int kt4 = 0; kt4 < 4; ++kt4) ci[kt4] = 0.5f * csq_l[(4 * w + kt4) * 16 + cl];

    // ---- single MFMA pass over 4 row-groups; accs retained for candidate select
    for (int g = 0; g < 4; ++g) {
        bf16x8 a0 = afp[(g * 2 + 0) * 64 + l];
        bf16x8 a1 = afp[(g * 2 + 1) * 64 + l];
        f32x4 acc[4];
        #pragma unroll
        for (int kt4 = 0; kt4 < 4; ++kt4) {               // 4 independent MFMA chains
            f32x4 a = {ci[kt4], ci[kt4], ci[kt4], ci[kt4]};
            a = __builtin_amdgcn_mfma_f32_16x16x32_bf16(a0, bw0[kt4], a, 0, 0, 0);
            a = __builtin_amdgcn_mfma_f32_16x16x32_bf16(a1, bw1[kt4], a, 0, 0, 0);
            acc[kt4] = a;
        }
        // in-wave per-row min over this wave's 64 cols
        float mn[4];
        #pragma unroll
        for (int rg = 0; rg < 4; ++rg)
            mn[rg] = fminf(fminf(acc[0][rg], acc[1][rg]), fminf(acc[2][rg], acc[3][rg]));
        #pragma unroll
        for (int off = 1; off < 16; off <<= 1)
            #pragma unroll
            for (int rg = 0; rg < 4; ++rg)
                mn[rg] = fminf(mn[rg], __shfl_xor(mn[rg], off, 64));
        if (cl == 0) {
            #pragma unroll
            for (int rg = 0; rg < 4; ++rg) minw[4 * g4 + rg][w] = mn[rg];
        }
        __syncthreads();                                  // minw complete
        if (t < 16) {
            float m = minw[t][0];
            #pragma unroll
            for (int w2 = 1; w2 < 8; ++w2) m = fminf(m, minw[t][w2]);
            thrA[t] = m + marg[g * 16 + t];               // bound proven R6-R11
        }
        __syncthreads();                                  // thrA ready
        #pragma unroll
        for (int rg = 0; rg < 4; ++rg) {
            const float thr = thrA[4 * g4 + rg];          // broadcast read
            const int r = g * 16 + 4 * g4 + rg;
            #pragma unroll
            for (int kt4 = 0; kt4 < 4; ++kt4) {
                if (acc[kt4][rg] <= thr) {
                    int pos = atomicAdd(&cnts[r], 1);
                    if (pos < CMAX) cand[r][pos] = (unsigned short)(64 * w + kt4 * 16 + cl);
                }
            }
        }
    }
    __syncthreads();                                      // all candidates in

    // ---- exact fp32 refine: 8 slot-threads per row, x from LDS, lex tie-break
    {
        const int rr = t >> 3, slot = t & 7;
        const int n = cnts[rr];
        if (n <= CMAX) {                                  // n >= 1 (min qualifies)
            float bb = INFINITY; int bkk = 0x7fffffff;
            const float xsqe = xsqa[rr];
            for (int s = slot; s < n; s += 8) {
                int k = cand[rr][s];
                const float4* __restrict__ c4 = (const float4*)(cw + (size_t)k * DIM);
                float d0 = 0.f, d1 = 0.f, d2 = 0.f, d3 = 0.f;
                #pragma unroll
                for (int i = 0; i < 16; ++i) {
                    float4 c = c4[i];
                    d0 = fmaf(xl[(4 * i + 0) * XP + rr], c.x, d0);
                    d1 = fmaf(xl[(4 * i + 1) * XP + rr], c.y, d1);
                    d2 = fmaf(xl[(4 * i + 2) * XP + rr], c.z, d2);
                    d3 = fmaf(xl[(4 * i + 3) * XP + rr], c.w, d3);
                }
                float dot  = (d0 + d1) + (d2 + d3);
                float dist = (xsqe + csq_l[k]) - 2.f * dot;   // reference rounding order
                if (dist < bb || (dist == bb && k < bkk)) { bb = dist; bkk = k; }
            }
            #pragma unroll
            for (int off = 1; off < 8; off <<= 1) {
                float ob = __shfl_xor(bb, off, 64);
                int   ok = __shfl_xor(bkk, off, 64);
                if (ob < bb || (ob == bb && ok < bkk)) { bb = ob; bkk = ok; }
            }
            if (slot == 0) {
                sidxl[rr] = bkk;
                out[(size_t)NROW * DIM + row0 + rr] = (float)bkk;
            }
        }
    }
    __syncthreads();

    // ---- rare overflow rows: one codeword per thread, block lex-argmin
    for (int r = 0; r < 64; ++r) {
        if (cnts[r] <= CMAX) continue;                    // block-uniform
        const float xsqe = xsqa[r];
        const int k = t;                                  // 512 threads = 512 codewords
        const float4* __restrict__ c4 = (const float4*)(cw + (size_t)k * DIM);
        float d0 = 0.f, d1 = 0.f, d2 = 0.f, d3 = 0.f;
        #pragma unroll
        for (int i = 0; i < 16; ++i) {
            float4 c = c4[i];
            d0 = fmaf(xl[(4 * i + 0) * XP + r], c.x, d0);
            d1 = fmaf(xl[(4 * i + 1) * XP + r], c.y, d1);
            d2 = fmaf(xl[(4 * i + 2) * XP + r], c.z, d2);
            d3 = fmaf(xl[(4 * i + 3) * XP + r], c.w, d3);
        }
        float dot = (d0 + d1) + (d2 + d3);
        float bb  = (xsqe + csq_l[k]) - 2.f * dot;
        int  bkk  = k;
        #pragma unroll
        for (int off = 32; off; off >>= 1) {
            float ob = __shfl_down(bb, off, 64);
            int   ok = __shfl_down(bkk, off, 64);
            if (ob < bb || (ob == bb && ok < bkk)) { bb = ob; bkk = ok; }
        }
        if (l == 0) { redf[w] = bb; redk[w] = bkk; }
        __syncthreads();
        if (t == 0) {
            float fb = redf[0]; int fk = redk[0];
            for (int w2 = 1; w2 < 8; ++w2)
                if (redf[w2] < fb || (redf[w2] == fb && redk[w2] < fk)) { fb = redf[w2]; fk = redk[w2]; }
            sidxl[r] = fk;
            out[(size_t)NROW * DIM + row0 + r] = (float)fk;
        }
        __syncthreads();
    }

    // ---- epilogue: gather codeword, write quantized NCHW, loss partial (x from LDS)
    {
        const int gr = t & 63, seg = t >> 6;              // seg wave-uniform, 8 dims each
        const int kwin = sidxl[gr];
        const float* __restrict__ qp = cw + (size_t)kwin * DIM + seg * 8;
        float* __restrict__ obase = out + (size_t)b * (DIM * HWSZ) + hw0 + gr;
        float lsum = 0.f;
        #pragma unroll
        for (int dd = 0; dd < 2; ++dd) {
            float4 q4 = *(const float4*)(qp + dd * 4);
            float qv[4] = {q4.x, q4.y, q4.z, q4.w};
            #pragma unroll
            for (int c = 0; c < 4; ++c) {
                int d = seg * 8 + dd * 4 + c;
                float xv = xl[d * XP + gr];
                obase[(size_t)d * HWSZ] = qv[c];
                float diff = qv[c] - xv;
                lsum = fmaf(diff, diff, lsum);
            }
        }
        #pragma unroll
        for (int off = 32; off; off >>= 1) lsum += __shfl_down(lsum, off, 64);
        if (l == 0) atomicAdd(&lossb, lsum);
    }
    __syncthreads();
    if (t == 0) part[blockIdx.x] = lossb;
}

__global__ void vq_finalize_kernel(const float* __restrict__ part, float* __restrict__ out) {
    __shared__ float wsum[4];
    const int t = threadIdx.x;
    float s = 0.f;
    #pragma unroll
    for (int i = 0; i < 8; ++i) s += part[t * 8 + i];     // fixed order: deterministic
    #pragma unroll
    for (int off = 32; off; off >>= 1) s += __shfl_down(s, off, 64);
    if ((t & 63) == 0) wsum[t >> 6] = s;
    __syncthreads();
    if (t == 0)
        out[(size_t)NROW * DIM + NROW] =
            1.25f * ((wsum[0] + wsum[1]) + (wsum[2] + wsum[3])) / (float)((size_t)NROW * DIM);
}

extern "C" void kernel_launch(void* const* d_in, const int* in_sizes, int n_in,
                              void* d_out, int out_size, void* d_ws, size_t ws_size,
                              hipStream_t stream) {
    const float* in = (const float*)d_in[0];
    const float* cw = (const float*)d_in[1];
    float* out = (float*)d_out;
    float* ws  = (float*)d_ws;

    hipLaunchKernelGGL(vq_prep_kernel, dim3(16), dim3(256), 0, stream, cw, ws);
    hipLaunchKernelGGL(vq_main_kernel, dim3(NROW / 64), dim3(512), 0, stream,
                       in, cw, ws, ws + WS_PART, out);
    hipLaunchKernelGGL(vq_finalize_kernel, dim3(1), dim3(256), 0, stream, ws + WS_PART, out);
}